// Round 1
// baseline (2215.621 us; speedup 1.0000x reference)
//
#include <hip/hip_runtime.h>
#include <math.h>

#define SLOPE 0.2f

static __device__ __forceinline__ float elu_f(float x){ return x > 0.f ? x : (__expf(x) - 1.f); }

// ---------------- CSR build ----------------
__global__ void __launch_bounds__(256) hist_kernel(const int* __restrict__ e0, int E, int* __restrict__ cnt){
    int i = blockIdx.x*256 + threadIdx.x;
    if (i < E) atomicAdd(&cnt[e0[i]], 1);
}

__global__ void __launch_bounds__(1024) scan_kernel(const int* __restrict__ cnt, int n,
                                                    int* __restrict__ row_ptr, int* __restrict__ cursor){
    __shared__ int wtot[16];
    __shared__ int carry_sh;
    if (threadIdx.x == 0) carry_sh = 0;
    __syncthreads();
    const int lane = threadIdx.x & 63, wid = threadIdx.x >> 6;
    const int nch = (n + 1023) >> 10;
    for (int c = 0; c < nch; ++c){
        int i = (c << 10) + threadIdx.x;
        int v = (i < n) ? cnt[i] : 0;
        int val = v;
        #pragma unroll
        for (int off = 1; off < 64; off <<= 1){
            int t = __shfl_up(val, off, 64);
            if (lane >= off) val += t;
        }
        if (lane == 63) wtot[wid] = val;
        __syncthreads();
        int tot = 0, wexcl = 0;
        #pragma unroll
        for (int w = 0; w < 16; ++w){ int t = wtot[w]; tot += t; if (w < wid) wexcl += t; }
        int excl = carry_sh + wexcl + (val - v);
        if (i < n){ row_ptr[i] = excl; cursor[i] = excl; }
        __syncthreads();
        if (threadIdx.x == 0) carry_sh += tot;
        __syncthreads();
    }
    if (threadIdx.x == 0) row_ptr[n] = carry_sh;
}

__global__ void __launch_bounds__(256) scatter_kernel(const int* __restrict__ e0, const int* __restrict__ e1, int E,
                                                      int* __restrict__ cursor, int* __restrict__ sidx){
    int i = blockIdx.x*256 + threadIdx.x;
    if (i < E){ int p = atomicAdd(&cursor[e0[i]], 1); sidx[p] = e1[i]; }
}

// ---------------- layer 1 GEMM: x[n,512] @ W1[head][512,64] -> h1g[n, 128] (2 heads/group) ----------------
__global__ void __launch_bounds__(256) gemm1_kernel(const float* __restrict__ x, const float* __restrict__ W1, int head0,
                                                    float* __restrict__ h1g, int n){
    __shared__ float As[32][128];   // [k][node]
    __shared__ float Ws[32][64];    // [k][f]
    const int tid = threadIdx.x;
    const int hy = blockIdx.y;      // head within group
    const float* W = W1 + (size_t)(head0 + hy)*512*64;
    const int base = blockIdx.x*128;
    const int tx = tid & 7, ty = tid >> 3;           // micro-tile: 4 nodes x 8 f
    const int srow = tid & 127, shalf = tid >> 7;    // staging: 2 threads/row, 16 k each
    float acc[4][8] = {};
    for (int k0 = 0; k0 < 512; k0 += 32){
        {   // stage A (transposed)
            int node = base + srow;
            const float* src = x + (size_t)node*512 + k0 + shalf*16;
            #pragma unroll
            for (int j = 0; j < 4; ++j){
                float4 v = (node < n) ? *(const float4*)(src + j*4) : make_float4(0.f,0.f,0.f,0.f);
                int kr = shalf*16 + j*4;
                As[kr+0][srow] = v.x; As[kr+1][srow] = v.y; As[kr+2][srow] = v.z; As[kr+3][srow] = v.w;
            }
        }
        {   // stage W
            #pragma unroll
            for (int j = 0; j < 2; ++j){
                int q = j*256 + tid;                 // float4 index over 32x16
                int kr = q >> 4, c4 = (q & 15) << 2;
                *(float4*)&Ws[kr][c4] = *(const float4*)(W + (size_t)(k0 + kr)*64 + c4);
            }
        }
        __syncthreads();
        #pragma unroll 8
        for (int kk = 0; kk < 32; ++kk){
            float a[4], b[8];
            *(float4*)a     = *(const float4*)&As[kk][ty*4];
            *(float4*)&b[0] = *(const float4*)&Ws[kk][tx*8];
            *(float4*)&b[4] = *(const float4*)&Ws[kk][tx*8 + 4];
            #pragma unroll
            for (int i = 0; i < 4; ++i)
                #pragma unroll
                for (int jj = 0; jj < 8; ++jj)
                    acc[i][jj] += a[i]*b[jj];
        }
        __syncthreads();
    }
    #pragma unroll
    for (int i = 0; i < 4; ++i){
        int node = base + ty*4 + i;
        if (node < n){
            float* dst = h1g + (size_t)node*128 + hy*64 + tx*8;
            *(float4*)dst     = make_float4(acc[i][0],acc[i][1],acc[i][2],acc[i][3]);
            *(float4*)(dst+4) = make_float4(acc[i][4],acc[i][5],acc[i][6],acc[i][7]);
        }
    }
}

// ---------------- attention scores: s_src/s_dst per (node, head) ----------------
__global__ void __launch_bounds__(256) scores1_kernel(const float* __restrict__ h1g, const float* __restrict__ a1, int head0,
                                                      float* __restrict__ ssrc, float* __restrict__ sdst, int n){
    int node = blockIdx.x*256 + threadIdx.x;
    int hy = blockIdx.y;
    if (node >= n) return;
    const float* hr = h1g + (size_t)node*128 + hy*64;
    const float* a  = a1 + (size_t)(head0 + hy)*128;
    float s0 = 0.f, s1 = 0.f;
    #pragma unroll
    for (int f = 0; f < 64; f += 4){
        float4 v = *(const float4*)(hr + f);
        float4 u = *(const float4*)(a + f);
        float4 w = *(const float4*)(a + 64 + f);
        s0 += v.x*u.x + v.y*u.y + v.z*u.z + v.w*u.w;
        s1 += v.x*w.x + v.y*w.y + v.z*w.z + v.w*w.w;
    }
    ssrc[(size_t)hy*n + node] = s0;
    sdst[(size_t)hy*n + node] = s1;
}

// ---------------- layer 1 aggregation: one wave per (node, head) ----------------
__global__ void __launch_bounds__(256) agg1_kernel(const float* __restrict__ h1g, const float* __restrict__ ssrc,
                                                   const float* __restrict__ sdstv,
                                                   const int* __restrict__ row_ptr, const int* __restrict__ sidx,
                                                   float* __restrict__ hcat, int n, int head0){
    const int w = threadIdx.x >> 6, lane = threadIdx.x & 63;
    const int hy = w & 1;
    const int node = blockIdx.x*2 + (w >> 1);
    if (node >= n) return;
    const int r0 = row_ptr[node], r1 = row_ptr[node+1];
    const float ss = ssrc[(size_t)hy*n + node];
    const float* sd = sdstv + (size_t)hy*n;
    float acc = 0.f, wsum = 0.f;
    for (int e = r0; e < r1; ++e){
        int j = sidx[e];
        float t = ss + sd[j];
        t = t > 0.f ? t : SLOPE*t;
        float wgt = __expf(t);
        wsum += wgt;
        acc += wgt * h1g[(size_t)j*128 + hy*64 + lane];
    }
    hcat[(size_t)node*512 + (head0 + hy)*64 + lane] = elu_f(acc / wsum);
}

// ---------------- layer 2 GEMM (+ scores fused): hcat[n,512] @ W2[512,20] ----------------
__global__ void __launch_bounds__(256) gemm2_kernel(const float* __restrict__ hcat, const float* __restrict__ W2,
                                                    const float* __restrict__ a2,
                                                    float* __restrict__ h2, float* __restrict__ ssrc,
                                                    float* __restrict__ sdst, int n){
    __shared__ float As[16][257];
    __shared__ float Ws[16][20];
    const int tid = threadIdx.x;
    const int base = blockIdx.x*256;
    const int node = base + tid;
    float acc[20] = {};
    for (int k0 = 0; k0 < 512; k0 += 16){
        const float* src = hcat + (size_t)node*512 + k0;
        #pragma unroll
        for (int j = 0; j < 4; ++j){
            float4 v = (node < n) ? *(const float4*)(src + j*4) : make_float4(0.f,0.f,0.f,0.f);
            As[j*4+0][tid] = v.x; As[j*4+1][tid] = v.y; As[j*4+2][tid] = v.z; As[j*4+3][tid] = v.w;
        }
        for (int q = tid; q < 320; q += 256){
            int kr = q/20, cc = q%20;
            Ws[kr][cc] = W2[(size_t)(k0 + kr)*20 + cc];
        }
        __syncthreads();
        #pragma unroll
        for (int kk = 0; kk < 16; ++kk){
            float a = As[kk][tid];
            #pragma unroll
            for (int cc = 0; cc < 20; ++cc) acc[cc] += a*Ws[kk][cc];
        }
        __syncthreads();
    }
    if (node < n){
        float s0 = 0.f, s1 = 0.f;
        #pragma unroll
        for (int cc = 0; cc < 20; ++cc){
            h2[(size_t)node*20 + cc] = acc[cc];
            s0 += acc[cc]*a2[cc];
            s1 += acc[cc]*a2[20 + cc];
        }
        ssrc[node] = s0; sdst[node] = s1;
    }
}

// ---------------- layer 2 aggregation: one wave per node ----------------
__global__ void __launch_bounds__(256) agg2_kernel(const float* __restrict__ h2, const float* __restrict__ ssrc,
                                                   const float* __restrict__ sdstv,
                                                   const int* __restrict__ row_ptr, const int* __restrict__ sidx,
                                                   float* __restrict__ out, int n){
    const int w = threadIdx.x >> 6, lane = threadIdx.x & 63;
    const int node = blockIdx.x*4 + w;
    if (node >= n) return;
    const int r0 = row_ptr[node], r1 = row_ptr[node+1];
    const float ss = ssrc[node];
    float acc = 0.f, wsum = 0.f;
    for (int e = r0; e < r1; ++e){
        int j = sidx[e];
        float t = ss + sdstv[j];
        t = t > 0.f ? t : SLOPE*t;
        float wgt = __expf(t);
        wsum += wgt;
        if (lane < 20) acc += wgt * h2[(size_t)j*20 + lane];
    }
    if (lane < 20) out[(size_t)node*20 + lane] = elu_f(acc / wsum);
}

extern "C" void kernel_launch(void* const* d_in, const int* in_sizes, int n_in,
                              void* d_out, int out_size, void* d_ws, size_t ws_size,
                              hipStream_t stream){
    const float* x  = (const float*)d_in[0];
    const float* W1 = (const float*)d_in[1];
    const float* a1 = (const float*)d_in[2];
    const float* W2 = (const float*)d_in[3];
    const float* a2 = (const float*)d_in[4];
    const int*   ei = (const int*)d_in[5];
    const int n = in_sizes[0] / 512;
    const int E = in_sizes[5] / 2;
    const int* e0 = ei;
    const int* e1 = ei + E;

    char* p = (char*)d_ws;
    auto alloc = [&](size_t bytes)->char*{ char* r = p; p += (bytes + 255) & ~(size_t)255; return r; };
    float* hcat    = (float*)alloc((size_t)n*512*4);   // 102.4 MB
    float* h1g     = (float*)alloc((size_t)n*128*4);   // 25.6 MB (2 heads)
    float* ssrc1   = (float*)alloc((size_t)n*2*4);
    float* sdst1   = (float*)alloc((size_t)n*2*4);
    int*   cnt     = (int*)  alloc((size_t)n*4);
    int*   row_ptr = (int*)  alloc(((size_t)n + 1)*4);
    int*   cursor  = (int*)  alloc((size_t)n*4);
    int*   sidx    = (int*)  alloc((size_t)E*4);       // 6.6 MB
    float* h2      = (float*)alloc((size_t)n*20*4);
    float* ssrc2   = (float*)alloc((size_t)n*4);
    float* sdst2   = (float*)alloc((size_t)n*4);

    // CSR by e0 (rebuilt every call; ws is re-poisoned)
    hipMemsetAsync(cnt, 0, (size_t)n*4, stream);
    const int eb = (E + 255)/256;
    hist_kernel<<<eb, 256, 0, stream>>>(e0, E, cnt);
    scan_kernel<<<1, 1024, 0, stream>>>(cnt, n, row_ptr, cursor);
    scatter_kernel<<<eb, 256, 0, stream>>>(e0, e1, E, cursor, sidx);

    const int mb = (n + 127)/128;
    const int nb256 = (n + 255)/256;
    for (int g = 0; g < 4; ++g){
        const int head0 = g*2;
        gemm1_kernel  <<<dim3(mb, 2),    256, 0, stream>>>(x, W1, head0, h1g, n);
        scores1_kernel<<<dim3(nb256, 2), 256, 0, stream>>>(h1g, a1, head0, ssrc1, sdst1, n);
        agg1_kernel   <<<(n + 1)/2,      256, 0, stream>>>(h1g, ssrc1, sdst1, row_ptr, sidx, hcat, n, head0);
    }
    gemm2_kernel<<<nb256, 256, 0, stream>>>(hcat, W2, a2, h2, ssrc2, sdst2, n);
    agg2_kernel <<<(n + 3)/4, 256, 0, stream>>>(h2, ssrc2, sdst2, row_ptr, sidx, (float*)d_out, n);
}

// Round 2
// 1407.571 us; speedup vs baseline: 1.5741x; 1.5741x over previous
//
#include <hip/hip_runtime.h>
#include <math.h>

#define SLOPE 0.2f

static __device__ __forceinline__ float elu_f(float x){ return x > 0.f ? x : (__expf(x) - 1.f); }
static __device__ __forceinline__ float lrelu(float t){ return t > 0.f ? t : SLOPE*t; }

// ---------------- CSR build ----------------
__global__ void __launch_bounds__(256) hist_kernel(const int* __restrict__ e0, int E, int* __restrict__ cnt){
    int i = blockIdx.x*256 + threadIdx.x;
    if (i < E) atomicAdd(&cnt[e0[i]], 1);
}

__global__ void __launch_bounds__(1024) scan_kernel(const int* __restrict__ cnt, int n,
                                                    int* __restrict__ row_ptr, int* __restrict__ cursor){
    __shared__ int wtot[16];
    __shared__ int carry_sh;
    if (threadIdx.x == 0) carry_sh = 0;
    __syncthreads();
    const int lane = threadIdx.x & 63, wid = threadIdx.x >> 6;
    const int nch = (n + 1023) >> 10;
    for (int c = 0; c < nch; ++c){
        int i = (c << 10) + threadIdx.x;
        int v = (i < n) ? cnt[i] : 0;
        int val = v;
        #pragma unroll
        for (int off = 1; off < 64; off <<= 1){
            int t = __shfl_up(val, off, 64);
            if (lane >= off) val += t;
        }
        if (lane == 63) wtot[wid] = val;
        __syncthreads();
        int tot = 0, wexcl = 0;
        #pragma unroll
        for (int w = 0; w < 16; ++w){ int t = wtot[w]; tot += t; if (w < wid) wexcl += t; }
        int excl = carry_sh + wexcl + (val - v);
        if (i < n){ row_ptr[i] = excl; cursor[i] = excl; }
        __syncthreads();
        if (threadIdx.x == 0) carry_sh += tot;
        __syncthreads();
    }
    if (threadIdx.x == 0) row_ptr[n] = carry_sh;
}

__global__ void __launch_bounds__(256) scatter_kernel(const int* __restrict__ e0, const int* __restrict__ e1, int E,
                                                      int* __restrict__ cursor, int* __restrict__ sidx){
    int i = blockIdx.x*256 + threadIdx.x;
    if (i < E){ int p = atomicAdd(&cursor[e0[i]], 1); sidx[p] = e1[i]; }
}

// ---------------- layer 1 GEMM: x[n,512] @ W1[head][512,64] -> h1g[n, 128] (2 heads/group) ----------------
__global__ void __launch_bounds__(256) gemm1_kernel(const float* __restrict__ x, const float* __restrict__ W1, int head0,
                                                    float* __restrict__ h1g, int n){
    __shared__ float As[32][128];   // [k][node]
    __shared__ float Ws[32][64];    // [k][f]
    const int tid = threadIdx.x;
    const int hy = blockIdx.y;      // head within group
    const float* W = W1 + (size_t)(head0 + hy)*512*64;
    const int base = blockIdx.x*128;
    const int tx = tid & 7, ty = tid >> 3;           // micro-tile: 4 nodes x 8 f
    const int srow = tid & 127, shalf = tid >> 7;    // staging: 2 threads/row, 16 k each
    float acc[4][8] = {};
    for (int k0 = 0; k0 < 512; k0 += 32){
        {   // stage A (transposed)
            int node = base + srow;
            const float* src = x + (size_t)node*512 + k0 + shalf*16;
            #pragma unroll
            for (int j = 0; j < 4; ++j){
                float4 v = (node < n) ? *(const float4*)(src + j*4) : make_float4(0.f,0.f,0.f,0.f);
                int kr = shalf*16 + j*4;
                As[kr+0][srow] = v.x; As[kr+1][srow] = v.y; As[kr+2][srow] = v.z; As[kr+3][srow] = v.w;
            }
        }
        {   // stage W
            #pragma unroll
            for (int j = 0; j < 2; ++j){
                int q = j*256 + tid;                 // float4 index over 32x16
                int kr = q >> 4, c4 = (q & 15) << 2;
                *(float4*)&Ws[kr][c4] = *(const float4*)(W + (size_t)(k0 + kr)*64 + c4);
            }
        }
        __syncthreads();
        #pragma unroll 8
        for (int kk = 0; kk < 32; ++kk){
            float a[4], b[8];
            *(float4*)a     = *(const float4*)&As[kk][ty*4];
            *(float4*)&b[0] = *(const float4*)&Ws[kk][tx*8];
            *(float4*)&b[4] = *(const float4*)&Ws[kk][tx*8 + 4];
            #pragma unroll
            for (int i = 0; i < 4; ++i)
                #pragma unroll
                for (int jj = 0; jj < 8; ++jj)
                    acc[i][jj] += a[i]*b[jj];
        }
        __syncthreads();
    }
    #pragma unroll
    for (int i = 0; i < 4; ++i){
        int node = base + ty*4 + i;
        if (node < n){
            float* dst = h1g + (size_t)node*128 + hy*64 + tx*8;
            *(float4*)dst     = make_float4(acc[i][0],acc[i][1],acc[i][2],acc[i][3]);
            *(float4*)(dst+4) = make_float4(acc[i][4],acc[i][5],acc[i][6],acc[i][7]);
        }
    }
}

// ---------------- attention scores: s_src/s_dst per (node, head) ----------------
__global__ void __launch_bounds__(256) scores1_kernel(const float* __restrict__ h1g, const float* __restrict__ a1, int head0,
                                                      float* __restrict__ ssrc, float* __restrict__ sdst, int n){
    int node = blockIdx.x*256 + threadIdx.x;
    int hy = blockIdx.y;
    if (node >= n) return;
    const float* hr = h1g + (size_t)node*128 + hy*64;
    const float* a  = a1 + (size_t)(head0 + hy)*128;
    float s0 = 0.f, s1 = 0.f;
    #pragma unroll
    for (int f = 0; f < 64; f += 4){
        float4 v = *(const float4*)(hr + f);
        float4 u = *(const float4*)(a + f);
        float4 w = *(const float4*)(a + 64 + f);
        s0 += v.x*u.x + v.y*u.y + v.z*u.z + v.w*u.w;
        s1 += v.x*w.x + v.y*w.y + v.z*w.z + v.w*w.w;
    }
    ssrc[(size_t)hy*n + node] = s0;
    sdst[(size_t)hy*n + node] = s1;
}

// ---------------- layer 1 aggregation: one wave per node, BOTH heads of the group ----------------
// lane 0..31 -> head0 features (float2 = f[2*lane], f[2*lane+1]); lane 32..63 -> head1.
__global__ void __launch_bounds__(256) agg1_kernel(const float* __restrict__ h1g, const float* __restrict__ ssrc,
                                                   const float* __restrict__ sdstv,
                                                   const int* __restrict__ row_ptr, const int* __restrict__ sidx,
                                                   float* __restrict__ hcat, int n, int head0){
    const int w = threadIdx.x >> 6, lane = threadIdx.x & 63;
    const int node = blockIdx.x*4 + w;
    if (node >= n) return;
    const int r0 = row_ptr[node], r1 = row_ptr[node+1];
    const int hy = lane >> 5;                       // this lane's head within group
    const float ssh = ssrc[(size_t)hy*n + node];
    const float* sdh = sdstv + (size_t)hy*n;
    float accx = 0.f, accy = 0.f, wsum = 0.f;
    int e = r0;
    for (; e + 3 < r1; e += 4){
        int j0 = sidx[e], j1 = sidx[e+1], j2 = sidx[e+2], j3 = sidx[e+3];
        // independent 512B row gathers (4 in flight)
        float2 v0 = *(const float2*)(h1g + (size_t)j0*128 + lane*2);
        float2 v1 = *(const float2*)(h1g + (size_t)j1*128 + lane*2);
        float2 v2 = *(const float2*)(h1g + (size_t)j2*128 + lane*2);
        float2 v3 = *(const float2*)(h1g + (size_t)j3*128 + lane*2);
        float s0 = sdh[j0], s1 = sdh[j1], s2 = sdh[j2], s3 = sdh[j3];
        float w0 = __expf(lrelu(ssh + s0));
        float w1 = __expf(lrelu(ssh + s1));
        float w2 = __expf(lrelu(ssh + s2));
        float w3 = __expf(lrelu(ssh + s3));
        accx += w0*v0.x + w1*v1.x + w2*v2.x + w3*v3.x;
        accy += w0*v0.y + w1*v1.y + w2*v2.y + w3*v3.y;
        wsum += (w0 + w1) + (w2 + w3);
    }
    for (; e < r1; ++e){
        int j = sidx[e];
        float2 v = *(const float2*)(h1g + (size_t)j*128 + lane*2);
        float wg = __expf(lrelu(ssh + sdh[j]));
        accx += wg*v.x; accy += wg*v.y; wsum += wg;
    }
    float inv = 1.f / wsum;
    float2 o; o.x = elu_f(accx*inv); o.y = elu_f(accy*inv);
    *(float2*)(hcat + (size_t)node*512 + head0*64 + lane*2) = o;
}

// ---------------- layer 2 GEMM (+ scores fused): hcat[n,512] @ W2[512,20] ----------------
__global__ void __launch_bounds__(256) gemm2_kernel(const float* __restrict__ hcat, const float* __restrict__ W2,
                                                    const float* __restrict__ a2,
                                                    float* __restrict__ h2, float* __restrict__ ssrc,
                                                    float* __restrict__ sdst, int n){
    __shared__ float As[16][257];
    __shared__ float Ws[16][20];
    const int tid = threadIdx.x;
    const int base = blockIdx.x*256;
    const int node = base + tid;
    float acc[20] = {};
    for (int k0 = 0; k0 < 512; k0 += 16){
        const float* src = hcat + (size_t)node*512 + k0;
        #pragma unroll
        for (int j = 0; j < 4; ++j){
            float4 v = (node < n) ? *(const float4*)(src + j*4) : make_float4(0.f,0.f,0.f,0.f);
            As[j*4+0][tid] = v.x; As[j*4+1][tid] = v.y; As[j*4+2][tid] = v.z; As[j*4+3][tid] = v.w;
        }
        for (int q = tid; q < 320; q += 256){
            int kr = q/20, cc = q%20;
            Ws[kr][cc] = W2[(size_t)(k0 + kr)*20 + cc];
        }
        __syncthreads();
        #pragma unroll
        for (int kk = 0; kk < 16; ++kk){
            float a = As[kk][tid];
            #pragma unroll
            for (int cc = 0; cc < 20; ++cc) acc[cc] += a*Ws[kk][cc];
        }
        __syncthreads();
    }
    if (node < n){
        float s0 = 0.f, s1 = 0.f;
        #pragma unroll
        for (int cc = 0; cc < 20; ++cc){
            h2[(size_t)node*20 + cc] = acc[cc];
            s0 += acc[cc]*a2[cc];
            s1 += acc[cc]*a2[20 + cc];
        }
        ssrc[node] = s0; sdst[node] = s1;
    }
}

// ---------------- layer 2 aggregation: one wave per node, unrolled ----------------
__global__ void __launch_bounds__(256) agg2_kernel(const float* __restrict__ h2, const float* __restrict__ ssrc,
                                                   const float* __restrict__ sdstv,
                                                   const int* __restrict__ row_ptr, const int* __restrict__ sidx,
                                                   float* __restrict__ out, int n){
    const int w = threadIdx.x >> 6, lane = threadIdx.x & 63;
    const int node = blockIdx.x*4 + w;
    if (node >= n) return;
    const int r0 = row_ptr[node], r1 = row_ptr[node+1];
    const float ss = ssrc[node];
    const bool act = lane < 20;
    float acc = 0.f, wsum = 0.f;
    int e = r0;
    for (; e + 3 < r1; e += 4){
        int j0 = sidx[e], j1 = sidx[e+1], j2 = sidx[e+2], j3 = sidx[e+3];
        float v0 = act ? h2[(size_t)j0*20 + lane] : 0.f;
        float v1 = act ? h2[(size_t)j1*20 + lane] : 0.f;
        float v2 = act ? h2[(size_t)j2*20 + lane] : 0.f;
        float v3 = act ? h2[(size_t)j3*20 + lane] : 0.f;
        float s0 = sdstv[j0], s1 = sdstv[j1], s2 = sdstv[j2], s3 = sdstv[j3];
        float w0 = __expf(lrelu(ss + s0));
        float w1 = __expf(lrelu(ss + s1));
        float w2 = __expf(lrelu(ss + s2));
        float w3 = __expf(lrelu(ss + s3));
        acc += w0*v0 + w1*v1 + w2*v2 + w3*v3;
        wsum += (w0 + w1) + (w2 + w3);
    }
    for (; e < r1; ++e){
        int j = sidx[e];
        float v = act ? h2[(size_t)j*20 + lane] : 0.f;
        float wg = __expf(lrelu(ss + sdstv[j]));
        acc += wg*v; wsum += wg;
    }
    if (act) out[(size_t)node*20 + lane] = elu_f(acc / wsum);
}

extern "C" void kernel_launch(void* const* d_in, const int* in_sizes, int n_in,
                              void* d_out, int out_size, void* d_ws, size_t ws_size,
                              hipStream_t stream){
    const float* x  = (const float*)d_in[0];
    const float* W1 = (const float*)d_in[1];
    const float* a1 = (const float*)d_in[2];
    const float* W2 = (const float*)d_in[3];
    const float* a2 = (const float*)d_in[4];
    const int*   ei = (const int*)d_in[5];
    const int n = in_sizes[0] / 512;
    const int E = in_sizes[5] / 2;
    const int* e0 = ei;
    const int* e1 = ei + E;

    char* p = (char*)d_ws;
    auto alloc = [&](size_t bytes)->char*{ char* r = p; p += (bytes + 255) & ~(size_t)255; return r; };
    float* hcat    = (float*)alloc((size_t)n*512*4);   // 102.4 MB
    float* h1g     = (float*)alloc((size_t)n*128*4);   // 25.6 MB (2 heads)
    float* ssrc1   = (float*)alloc((size_t)n*2*4);
    float* sdst1   = (float*)alloc((size_t)n*2*4);
    int*   cnt     = (int*)  alloc((size_t)n*4);
    int*   row_ptr = (int*)  alloc(((size_t)n + 1)*4);
    int*   cursor  = (int*)  alloc((size_t)n*4);
    int*   sidx    = (int*)  alloc((size_t)E*4);       // 6.6 MB
    float* h2      = (float*)alloc((size_t)n*20*4);
    float* ssrc2   = (float*)alloc((size_t)n*4);
    float* sdst2   = (float*)alloc((size_t)n*4);

    // CSR by e0 (rebuilt every call; ws is re-poisoned)
    hipMemsetAsync(cnt, 0, (size_t)n*4, stream);
    const int eb = (E + 255)/256;
    hist_kernel<<<eb, 256, 0, stream>>>(e0, E, cnt);
    scan_kernel<<<1, 1024, 0, stream>>>(cnt, n, row_ptr, cursor);
    scatter_kernel<<<eb, 256, 0, stream>>>(e0, e1, E, cursor, sidx);

    const int mb = (n + 127)/128;
    const int nb256 = (n + 255)/256;
    for (int g = 0; g < 4; ++g){
        const int head0 = g*2;
        gemm1_kernel  <<<dim3(mb, 2),    256, 0, stream>>>(x, W1, head0, h1g, n);
        scores1_kernel<<<dim3(nb256, 2), 256, 0, stream>>>(h1g, a1, head0, ssrc1, sdst1, n);
        agg1_kernel   <<<(n + 3)/4,      256, 0, stream>>>(h1g, ssrc1, sdst1, row_ptr, sidx, hcat, n, head0);
    }
    gemm2_kernel<<<nb256, 256, 0, stream>>>(hcat, W2, a2, h2, ssrc2, sdst2, n);
    agg2_kernel <<<(n + 3)/4, 256, 0, stream>>>(h2, ssrc2, sdst2, row_ptr, sidx, (float*)d_out, n);
}

// Round 3
// 1335.583 us; speedup vs baseline: 1.6589x; 1.0539x over previous
//
#include <hip/hip_runtime.h>
#include <math.h>

#define SLOPE 0.2f

static __device__ __forceinline__ float elu_f(float x){ return x > 0.f ? x : (__expf(x) - 1.f); }
static __device__ __forceinline__ float lrelu(float t){ return t > 0.f ? t : SLOPE*t; }

// ---------------- CSR build (XCD-sliced: block b -> node slice b%8, edge chunk b/8) ----------------
__global__ void __launch_bounds__(256) hist_sliced_kernel(const int* __restrict__ e0, int E, int n,
                                                          int* __restrict__ cnt){
    const int s = blockIdx.x & 7;
    const int c = blockIdx.x >> 3;
    const int K = gridDim.x >> 3;
    const int lo = (int)((long)s*n >> 3), hi = (int)((long)(s+1)*n >> 3);
    const int i0 = (int)((long)c*E/K), i1 = (int)((long)(c+1)*E/K);
    for (int i = i0 + threadIdx.x; i < i1; i += 256){
        int j = e0[i];
        if (j >= lo && j < hi) atomicAdd(&cnt[j], 1);
    }
}

__global__ void __launch_bounds__(1024) scan_kernel(const int* __restrict__ cnt, int n,
                                                    int* __restrict__ row_ptr, int* __restrict__ cursor){
    __shared__ int wtot[16];
    __shared__ int carry_sh;
    if (threadIdx.x == 0) carry_sh = 0;
    __syncthreads();
    const int lane = threadIdx.x & 63, wid = threadIdx.x >> 6;
    const int nch = (n + 1023) >> 10;
    for (int c = 0; c < nch; ++c){
        int i = (c << 10) + threadIdx.x;
        int v = (i < n) ? cnt[i] : 0;
        int val = v;
        #pragma unroll
        for (int off = 1; off < 64; off <<= 1){
            int t = __shfl_up(val, off, 64);
            if (lane >= off) val += t;
        }
        if (lane == 63) wtot[wid] = val;
        __syncthreads();
        int tot = 0, wexcl = 0;
        #pragma unroll
        for (int w = 0; w < 16; ++w){ int t = wtot[w]; tot += t; if (w < wid) wexcl += t; }
        int excl = carry_sh + wexcl + (val - v);
        if (i < n){ row_ptr[i] = excl; cursor[i] = excl; }
        __syncthreads();
        if (threadIdx.x == 0) carry_sh += tot;
        __syncthreads();
    }
    if (threadIdx.x == 0) row_ptr[n] = carry_sh;
}

__global__ void __launch_bounds__(256) scatter_sliced_kernel(const int* __restrict__ e0, const int* __restrict__ e1,
                                                             int E, int n,
                                                             int* __restrict__ cursor, int* __restrict__ sidx){
    const int s = blockIdx.x & 7;
    const int c = blockIdx.x >> 3;
    const int K = gridDim.x >> 3;
    const int lo = (int)((long)s*n >> 3), hi = (int)((long)(s+1)*n >> 3);
    const int i0 = (int)((long)c*E/K), i1 = (int)((long)(c+1)*E/K);
    for (int i = i0 + threadIdx.x; i < i1; i += 256){
        int j = e0[i];
        if (j >= lo && j < hi){
            int p = atomicAdd(&cursor[j], 1);
            sidx[p] = e1[i];
        }
    }
}

// ---------------- layer 1 GEMM + fused scores: x[n,512] @ W1[head][512,64] -> h_g[n, G*64] ----------------
// grid (mb, G); hy = blockIdx.y = head within group; head = head0 + hy.
__global__ void __launch_bounds__(256) gemm1_kernel(const float* __restrict__ x, const float* __restrict__ W1,
                                                    const float* __restrict__ a1, int head0, int G,
                                                    float* __restrict__ h_g, float* __restrict__ ssrc_g,
                                                    float* __restrict__ sdst_g, int n){
    __shared__ float As[32][128];   // [k][node]
    __shared__ float Ws[32][64];    // [k][f]
    const int tid = threadIdx.x;
    const int hy = blockIdx.y;
    const int head = head0 + hy;
    const float* W = W1 + (size_t)head*512*64;
    const int base = blockIdx.x*128;
    const int tx = tid & 7, ty = tid >> 3;           // micro-tile: 4 nodes x 8 f
    const int srow = tid & 127, shalf = tid >> 7;    // staging: 2 threads/row, 16 k each
    // attention vectors for this head's feature slice
    float asrc[8], adst[8];
    #pragma unroll
    for (int j = 0; j < 8; ++j){
        asrc[j] = a1[(size_t)head*128 + tx*8 + j];
        adst[j] = a1[(size_t)head*128 + 64 + tx*8 + j];
    }
    float acc[4][8] = {};
    for (int k0 = 0; k0 < 512; k0 += 32){
        {   // stage A (transposed)
            int node = base + srow;
            const float* src = x + (size_t)node*512 + k0 + shalf*16;
            #pragma unroll
            for (int j = 0; j < 4; ++j){
                float4 v = (node < n) ? *(const float4*)(src + j*4) : make_float4(0.f,0.f,0.f,0.f);
                int kr = shalf*16 + j*4;
                As[kr+0][srow] = v.x; As[kr+1][srow] = v.y; As[kr+2][srow] = v.z; As[kr+3][srow] = v.w;
            }
        }
        {   // stage W
            #pragma unroll
            for (int j = 0; j < 2; ++j){
                int q = j*256 + tid;                 // float4 index over 32x16
                int kr = q >> 4, c4 = (q & 15) << 2;
                *(float4*)&Ws[kr][c4] = *(const float4*)(W + (size_t)(k0 + kr)*64 + c4);
            }
        }
        __syncthreads();
        #pragma unroll 8
        for (int kk = 0; kk < 32; ++kk){
            float a[4], b[8];
            *(float4*)a     = *(const float4*)&As[kk][ty*4];
            *(float4*)&b[0] = *(const float4*)&Ws[kk][tx*8];
            *(float4*)&b[4] = *(const float4*)&Ws[kk][tx*8 + 4];
            #pragma unroll
            for (int i = 0; i < 4; ++i)
                #pragma unroll
                for (int jj = 0; jj < 8; ++jj)
                    acc[i][jj] += a[i]*b[jj];
        }
        __syncthreads();
    }
    const int GW = G*64;
    #pragma unroll
    for (int i = 0; i < 4; ++i){
        int node = base + ty*4 + i;
        // scores: per-thread partial dot over its 8 features, reduce over the 8 tx lanes
        float ps = 0.f, pd = 0.f;
        #pragma unroll
        for (int jj = 0; jj < 8; ++jj){ ps += acc[i][jj]*asrc[jj]; pd += acc[i][jj]*adst[jj]; }
        ps += __shfl_xor(ps, 1); pd += __shfl_xor(pd, 1);
        ps += __shfl_xor(ps, 2); pd += __shfl_xor(pd, 2);
        ps += __shfl_xor(ps, 4); pd += __shfl_xor(pd, 4);
        if (node < n){
            float* dst = h_g + (size_t)node*GW + hy*64 + tx*8;
            *(float4*)dst     = make_float4(acc[i][0],acc[i][1],acc[i][2],acc[i][3]);
            *(float4*)(dst+4) = make_float4(acc[i][4],acc[i][5],acc[i][6],acc[i][7]);
            if (tx == 0){
                ssrc_g[(size_t)node*G + hy] = ps;
                sdst_g[(size_t)node*G + hy] = pd;
            }
        }
    }
}

// ---------------- layer 1 aggregation: one wave per node, G heads at once ----------------
// G=4: lane -> float4 at offset lane*4 of the node's G*64=256-float row. head = lane>>4.
// G=2: lane -> float2 at offset lane*2 of the 128-float row. head = lane>>5.
template<int G>
__global__ void __launch_bounds__(256) agg1_kernel(const float* __restrict__ h_g, const float* __restrict__ ssrc_g,
                                                   const float* __restrict__ sdst_g,
                                                   const int* __restrict__ row_ptr, const int* __restrict__ sidx,
                                                   float* __restrict__ hcat, int n, int gpass){
    const int w = threadIdx.x >> 6, lane = threadIdx.x & 63;
    const int node = blockIdx.x*4 + w;
    if (node >= n) return;
    const int r0 = row_ptr[node], r1 = row_ptr[node+1];
    constexpr int GW = G*64;                 // floats per node row
    constexpr int V  = GW/64;                // floats per lane (4 or 2)
    const int h = lane / (64/G);             // this lane's head within group
    const float ssh = ssrc_g[(size_t)node*G + h];
    float acc[V] = {};
    float wsum = 0.f;
    int e = r0;
    for (; e + 3 < r1; e += 4){
        int j0 = sidx[e], j1 = sidx[e+1], j2 = sidx[e+2], j3 = sidx[e+3];
        const float* p0 = h_g + (size_t)j0*GW + lane*V;
        const float* p1 = h_g + (size_t)j1*GW + lane*V;
        const float* p2 = h_g + (size_t)j2*GW + lane*V;
        const float* p3 = h_g + (size_t)j3*GW + lane*V;
        float v0[V], v1[V], v2[V], v3[V];
        #pragma unroll
        for (int q = 0; q < V; ++q){ v0[q]=p0[q]; v1[q]=p1[q]; v2[q]=p2[q]; v3[q]=p3[q]; }
        float s0 = sdst_g[(size_t)j0*G + h];
        float s1 = sdst_g[(size_t)j1*G + h];
        float s2 = sdst_g[(size_t)j2*G + h];
        float s3 = sdst_g[(size_t)j3*G + h];
        float w0 = __expf(lrelu(ssh + s0));
        float w1 = __expf(lrelu(ssh + s1));
        float w2 = __expf(lrelu(ssh + s2));
        float w3 = __expf(lrelu(ssh + s3));
        #pragma unroll
        for (int q = 0; q < V; ++q) acc[q] += w0*v0[q] + w1*v1[q] + w2*v2[q] + w3*v3[q];
        wsum += (w0 + w1) + (w2 + w3);
    }
    for (; e < r1; ++e){
        int j = sidx[e];
        const float* p = h_g + (size_t)j*GW + lane*V;
        float wg = __expf(lrelu(ssh + sdst_g[(size_t)j*G + h]));
        #pragma unroll
        for (int q = 0; q < V; ++q) acc[q] += wg*p[q];
        wsum += wg;
    }
    float inv = 1.f / wsum;
    float* dst = hcat + (size_t)node*512 + gpass*GW + lane*V;
    #pragma unroll
    for (int q = 0; q < V; ++q) dst[q] = elu_f(acc[q]*inv);
}

// ---------------- layer 2 GEMM (+ scores fused): hcat[n,512] @ W2[512,20] ----------------
__global__ void __launch_bounds__(256) gemm2_kernel(const float* __restrict__ hcat, const float* __restrict__ W2,
                                                    const float* __restrict__ a2,
                                                    float* __restrict__ h2, float* __restrict__ ssrc,
                                                    float* __restrict__ sdst, int n){
    __shared__ float As[16][257];
    __shared__ float Ws[16][20];
    const int tid = threadIdx.x;
    const int base = blockIdx.x*256;
    const int node = base + tid;
    float acc[20] = {};
    for (int k0 = 0; k0 < 512; k0 += 16){
        const float* src = hcat + (size_t)node*512 + k0;
        #pragma unroll
        for (int j = 0; j < 4; ++j){
            float4 v = (node < n) ? *(const float4*)(src + j*4) : make_float4(0.f,0.f,0.f,0.f);
            As[j*4+0][tid] = v.x; As[j*4+1][tid] = v.y; As[j*4+2][tid] = v.z; As[j*4+3][tid] = v.w;
        }
        for (int q = tid; q < 320; q += 256){
            int kr = q/20, cc = q%20;
            Ws[kr][cc] = W2[(size_t)(k0 + kr)*20 + cc];
        }
        __syncthreads();
        #pragma unroll
        for (int kk = 0; kk < 16; ++kk){
            float a = As[kk][tid];
            #pragma unroll
            for (int cc = 0; cc < 20; ++cc) acc[cc] += a*Ws[kk][cc];
        }
        __syncthreads();
    }
    if (node < n){
        float s0 = 0.f, s1 = 0.f;
        #pragma unroll
        for (int cc = 0; cc < 20; ++cc){
            h2[(size_t)node*20 + cc] = acc[cc];
            s0 += acc[cc]*a2[cc];
            s1 += acc[cc]*a2[20 + cc];
        }
        ssrc[node] = s0; sdst[node] = s1;
    }
}

// ---------------- layer 2 aggregation: one wave per node, unrolled ----------------
__global__ void __launch_bounds__(256) agg2_kernel(const float* __restrict__ h2, const float* __restrict__ ssrc,
                                                   const float* __restrict__ sdstv,
                                                   const int* __restrict__ row_ptr, const int* __restrict__ sidx,
                                                   float* __restrict__ out, int n){
    const int w = threadIdx.x >> 6, lane = threadIdx.x & 63;
    const int node = blockIdx.x*4 + w;
    if (node >= n) return;
    const int r0 = row_ptr[node], r1 = row_ptr[node+1];
    const float ss = ssrc[node];
    const bool act = lane < 20;
    float acc = 0.f, wsum = 0.f;
    int e = r0;
    for (; e + 3 < r1; e += 4){
        int j0 = sidx[e], j1 = sidx[e+1], j2 = sidx[e+2], j3 = sidx[e+3];
        float v0 = act ? h2[(size_t)j0*20 + lane] : 0.f;
        float v1 = act ? h2[(size_t)j1*20 + lane] : 0.f;
        float v2 = act ? h2[(size_t)j2*20 + lane] : 0.f;
        float v3 = act ? h2[(size_t)j3*20 + lane] : 0.f;
        float s0 = sdstv[j0], s1 = sdstv[j1], s2 = sdstv[j2], s3 = sdstv[j3];
        float w0 = __expf(lrelu(ss + s0));
        float w1 = __expf(lrelu(ss + s1));
        float w2 = __expf(lrelu(ss + s2));
        float w3 = __expf(lrelu(ss + s3));
        acc += w0*v0 + w1*v1 + w2*v2 + w3*v3;
        wsum += (w0 + w1) + (w2 + w3);
    }
    for (; e < r1; ++e){
        int j = sidx[e];
        float v = act ? h2[(size_t)j*20 + lane] : 0.f;
        float wg = __expf(lrelu(ss + sdstv[j]));
        acc += wg*v; wsum += wg;
    }
    if (act) out[(size_t)node*20 + lane] = elu_f(acc / wsum);
}

extern "C" void kernel_launch(void* const* d_in, const int* in_sizes, int n_in,
                              void* d_out, int out_size, void* d_ws, size_t ws_size,
                              hipStream_t stream){
    const float* x  = (const float*)d_in[0];
    const float* W1 = (const float*)d_in[1];
    const float* a1 = (const float*)d_in[2];
    const float* W2 = (const float*)d_in[3];
    const float* a2 = (const float*)d_in[4];
    const int*   ei = (const int*)d_in[5];
    const int n = in_sizes[0] / 512;
    const int E = in_sizes[5] / 2;
    const int* e0 = ei;
    const int* e1 = ei + E;

    // workspace budget: choose 4-head groups if it fits, else 2-head groups
    auto total_need = [&](int G)->size_t{
        size_t t = 0;
        auto rnd = [&](size_t b){ t += (b + 255) & ~(size_t)255; };
        rnd((size_t)n*512*4);        // hcat
        rnd((size_t)n*G*64*4);       // h_g
        rnd((size_t)n*G*4);          // ssrc_g
        rnd((size_t)n*G*4);          // sdst_g
        rnd((size_t)n*4);            // cnt
        rnd(((size_t)n+1)*4);        // row_ptr
        rnd((size_t)n*4);            // cursor
        rnd((size_t)E*4);            // sidx
        rnd((size_t)n*20*4);         // h2
        rnd((size_t)n*4);            // ssrc2
        rnd((size_t)n*4);            // sdst2
        return t;
    };
    const int G = (ws_size >= total_need(4)) ? 4 : 2;

    char* p = (char*)d_ws;
    auto alloc = [&](size_t bytes)->char*{ char* r = p; p += (bytes + 255) & ~(size_t)255; return r; };
    float* hcat    = (float*)alloc((size_t)n*512*4);
    float* h_g     = (float*)alloc((size_t)n*G*64*4);
    float* ssrc_g  = (float*)alloc((size_t)n*G*4);
    float* sdst_g  = (float*)alloc((size_t)n*G*4);
    int*   cnt     = (int*)  alloc((size_t)n*4);
    int*   row_ptr = (int*)  alloc(((size_t)n + 1)*4);
    int*   cursor  = (int*)  alloc((size_t)n*4);
    int*   sidx    = (int*)  alloc((size_t)E*4);
    float* h2      = (float*)alloc((size_t)n*20*4);
    float* ssrc2   = (float*)alloc((size_t)n*4);
    float* sdst2   = (float*)alloc((size_t)n*4);

    // CSR by e0, XCD-sliced (rebuilt every call; ws is re-poisoned)
    hipMemsetAsync(cnt, 0, (size_t)n*4, stream);
    const int KCH = 192;                    // edge chunks per slice
    hist_sliced_kernel   <<<KCH*8, 256, 0, stream>>>(e0, E, n, cnt);
    scan_kernel          <<<1, 1024, 0, stream>>>(cnt, n, row_ptr, cursor);
    scatter_sliced_kernel<<<KCH*8, 256, 0, stream>>>(e0, e1, E, n, cursor, sidx);

    const int mb = (n + 127)/128;
    const int nb256 = (n + 255)/256;
    const int npass = 8 / G;
    for (int g = 0; g < npass; ++g){
        const int head0 = g*G;
        gemm1_kernel<<<dim3(mb, G), 256, 0, stream>>>(x, W1, a1, head0, G, h_g, ssrc_g, sdst_g, n);
        if (G == 4)
            agg1_kernel<4><<<(n + 3)/4, 256, 0, stream>>>(h_g, ssrc_g, sdst_g, row_ptr, sidx, hcat, n, g);
        else
            agg1_kernel<2><<<(n + 3)/4, 256, 0, stream>>>(h_g, ssrc_g, sdst_g, row_ptr, sidx, hcat, n, g);
    }
    gemm2_kernel<<<nb256, 256, 0, stream>>>(hcat, W2, a2, h2, ssrc2, sdst2, n);
    agg2_kernel <<<(n + 3)/4, 256, 0, stream>>>(h2, ssrc2, sdst2, row_ptr, sidx, (float*)d_out, n);
}

// Round 4
// 1027.490 us; speedup vs baseline: 2.1563x; 1.2998x over previous
//
#include <hip/hip_runtime.h>
#include <hip/hip_fp16.h>
#include <math.h>

#define SLOPE 0.2f

typedef short bf16x8 __attribute__((ext_vector_type(8)));
typedef float f32x4  __attribute__((ext_vector_type(4)));

static __device__ __forceinline__ float elu_f(float x){ return x > 0.f ? x : (__expf(x) - 1.f); }
static __device__ __forceinline__ float lrelu(float t){ return t > 0.f ? t : SLOPE*t; }
static __device__ __forceinline__ unsigned short f2bf_rne(float f){
    unsigned int u = __float_as_uint(f);
    unsigned int r = (u + 0x7FFFu + ((u >> 16) & 1u)) >> 16;
    return (unsigned short)r;
}
static __device__ __forceinline__ float bf2f(unsigned short h){ return __uint_as_float(((unsigned int)h) << 16); }

// ---------------- CSR build (XCD-sliced) ----------------
__global__ void __launch_bounds__(256) hist_sliced_kernel(const int* __restrict__ e0, int E, int n,
                                                          int* __restrict__ cnt){
    const int s = blockIdx.x & 7;
    const int c = blockIdx.x >> 3;
    const int K = gridDim.x >> 3;
    const int lo = (int)((long)s*n >> 3), hi = (int)((long)(s+1)*n >> 3);
    const int i0 = (int)((long)c*E/K), i1 = (int)((long)(c+1)*E/K);
    for (int i = i0 + threadIdx.x; i < i1; i += 256){
        int j = e0[i];
        if (j >= lo && j < hi) atomicAdd(&cnt[j], 1);
    }
}

__global__ void __launch_bounds__(1024) scan_kernel(const int* __restrict__ cnt, int n,
                                                    int* __restrict__ row_ptr, int* __restrict__ cursor){
    __shared__ int wtot[16];
    __shared__ int carry_sh;
    if (threadIdx.x == 0) carry_sh = 0;
    __syncthreads();
    const int lane = threadIdx.x & 63, wid = threadIdx.x >> 6;
    const int nch = (n + 1023) >> 10;
    for (int c = 0; c < nch; ++c){
        int i = (c << 10) + threadIdx.x;
        int v = (i < n) ? cnt[i] : 0;
        int val = v;
        #pragma unroll
        for (int off = 1; off < 64; off <<= 1){
            int t = __shfl_up(val, off, 64);
            if (lane >= off) val += t;
        }
        if (lane == 63) wtot[wid] = val;
        __syncthreads();
        int tot = 0, wexcl = 0;
        #pragma unroll
        for (int w = 0; w < 16; ++w){ int t = wtot[w]; tot += t; if (w < wid) wexcl += t; }
        int excl = carry_sh + wexcl + (val - v);
        if (i < n){ row_ptr[i] = excl; cursor[i] = excl; }
        __syncthreads();
        if (threadIdx.x == 0) carry_sh += tot;
        __syncthreads();
    }
    if (threadIdx.x == 0) row_ptr[n] = carry_sh;
}

__global__ void __launch_bounds__(256) scatter_sliced_kernel(const int* __restrict__ e0, const int* __restrict__ e1,
                                                             int E, int n,
                                                             int* __restrict__ cursor, int* __restrict__ sidx){
    const int s = blockIdx.x & 7;
    const int c = blockIdx.x >> 3;
    const int K = gridDim.x >> 3;
    const int lo = (int)((long)s*n >> 3), hi = (int)((long)(s+1)*n >> 3);
    const int i0 = (int)((long)c*E/K), i1 = (int)((long)(c+1)*E/K);
    for (int i = i0 + threadIdx.x; i < i1; i += 256){
        int j = e0[i];
        if (j >= lo && j < hi){
            int p = atomicAdd(&cursor[j], 1);
            sidx[p] = e1[i];
        }
    }
}

// ---------------- prep: split x into bf16 hi/lo ----------------
__global__ void __launch_bounds__(256) split_x_kernel(const float* __restrict__ x,
                                                      unsigned short* __restrict__ xhi,
                                                      unsigned short* __restrict__ xlo, int total4){
    int i = blockIdx.x*256 + threadIdx.x;
    if (i >= total4) return;
    float4 v = ((const float4*)x)[i];
    ushort4 h, l;
    h.x = f2bf_rne(v.x); l.x = f2bf_rne(v.x - bf2f(h.x));
    h.y = f2bf_rne(v.y); l.y = f2bf_rne(v.y - bf2f(h.y));
    h.z = f2bf_rne(v.z); l.z = f2bf_rne(v.z - bf2f(h.z));
    h.w = f2bf_rne(v.w); l.w = f2bf_rne(v.w - bf2f(h.w));
    ((ushort4*)xhi)[i] = h;
    ((ushort4*)xlo)[i] = l;
}

// ---------------- prep: transpose W1 [8][512][64] -> wT [8][64][512] bf16 hi/lo ----------------
__global__ void __launch_bounds__(256) prep_w_kernel(const float* __restrict__ W1,
                                                     unsigned short* __restrict__ wThi,
                                                     unsigned short* __restrict__ wTlo){
    int idx = blockIdx.x*256 + threadIdx.x;          // 8*64*512 = 262144
    int head = idx >> 15, rem = idx & 32767;
    int c = rem >> 9, k = rem & 511;
    float f = W1[((size_t)head << 15) + k*64 + c];
    unsigned short h = f2bf_rne(f);
    wThi[idx] = h;
    wTlo[idx] = f2bf_rne(f - bf2f(h));
}

// ---------------- layer 1: split-bf16 MFMA GEMM + fused scores ----------------
// grid (mb, 4); block = 4 waves; block computes 128 nodes x 2 heads (x64 feats).
// wave: 32 nodes x 128 cols via mfma_f32_16x16x32_bf16; acc = hi*hi + hi*lo + lo*hi.
__global__ void __launch_bounds__(256) gemm1_mfma_kernel(const unsigned short* __restrict__ xhi,
                                                         const unsigned short* __restrict__ xlo,
                                                         const unsigned short* __restrict__ wThi,
                                                         const unsigned short* __restrict__ wTlo,
                                                         const float* __restrict__ a1,
                                                         __half* __restrict__ h_g,
                                                         float* __restrict__ ssrc, float* __restrict__ sdst, int n){
    const int w = threadIdx.x >> 6, lane = threadIdx.x & 63;
    const int hb2 = blockIdx.y*2;                 // first head of this block
    const int base = blockIdx.x*128 + w*32;
    const int lr = lane & 15, lk = lane >> 4;     // frag row/col index and k-group
    f32x4 acc[2][8] = {};                         // [mi][hh*4+ni]
    const bf16x8 zf = {0,0,0,0,0,0,0,0};
    // per-mi row pointers (element offsets)
    const int r0 = base + lr, r1 = base + 16 + lr;
    const size_t ro0 = (size_t)r0*512 + lk*8;
    const size_t ro1 = (size_t)r1*512 + lk*8;
    for (int k0 = 0; k0 < 512; k0 += 32){
        bf16x8 ah[2], al[2];
        if (r0 < n){ ah[0] = *(const bf16x8*)(xhi + ro0 + k0); al[0] = *(const bf16x8*)(xlo + ro0 + k0); }
        else        { ah[0] = zf; al[0] = zf; }
        if (r1 < n){ ah[1] = *(const bf16x8*)(xhi + ro1 + k0); al[1] = *(const bf16x8*)(xlo + ro1 + k0); }
        else        { ah[1] = zf; al[1] = zf; }
        #pragma unroll
        for (int hh = 0; hh < 2; ++hh){
            const unsigned short* whp = wThi + (((size_t)(hb2+hh)) << 15) + k0 + lk*8;
            const unsigned short* wlp = wTlo + (((size_t)(hb2+hh)) << 15) + k0 + lk*8;
            #pragma unroll
            for (int ni = 0; ni < 4; ++ni){
                bf16x8 bh = *(const bf16x8*)(whp + (size_t)(ni*16 + lr)*512);
                bf16x8 bl = *(const bf16x8*)(wlp + (size_t)(ni*16 + lr)*512);
                #pragma unroll
                for (int mi = 0; mi < 2; ++mi){
                    f32x4& A = acc[mi][hh*4+ni];
                    A = __builtin_amdgcn_mfma_f32_16x16x32_bf16(ah[mi], bh, A, 0, 0, 0);
                    A = __builtin_amdgcn_mfma_f32_16x16x32_bf16(ah[mi], bl, A, 0, 0, 0);
                    A = __builtin_amdgcn_mfma_f32_16x16x32_bf16(al[mi], bh, A, 0, 0, 0);
                }
            }
        }
    }
    // epilogue: D layout: col = lane&15, row(within 16-tile) = (lane>>4)*4 + reg
    #pragma unroll
    for (int hh = 0; hh < 2; ++hh){
        const int head = hb2 + hh;
        float as_[4], ad_[4];
        #pragma unroll
        for (int ni = 0; ni < 4; ++ni){
            as_[ni] = a1[(size_t)head*128 + ni*16 + lr];
            ad_[ni] = a1[(size_t)head*128 + 64 + ni*16 + lr];
        }
        #pragma unroll
        for (int mi = 0; mi < 2; ++mi){
            #pragma unroll
            for (int reg = 0; reg < 4; ++reg){
                float s = 0.f, d = 0.f;
                #pragma unroll
                for (int ni = 0; ni < 4; ++ni){
                    float v = acc[mi][hh*4+ni][reg];
                    s += v*as_[ni]; d += v*ad_[ni];
                }
                s += __shfl_xor(s, 1); d += __shfl_xor(d, 1);
                s += __shfl_xor(s, 2); d += __shfl_xor(d, 2);
                s += __shfl_xor(s, 4); d += __shfl_xor(d, 4);
                s += __shfl_xor(s, 8); d += __shfl_xor(d, 8);
                const int node = base + mi*16 + lk*4 + reg;
                if (node < n){
                    #pragma unroll
                    for (int ni = 0; ni < 4; ++ni)
                        h_g[(size_t)node*512 + head*64 + ni*16 + lr] = __float2half(acc[mi][hh*4+ni][reg]);
                    if (lr == 0){
                        ssrc[(size_t)node*8 + head] = s;
                        sdst[(size_t)node*8 + head] = d;
                    }
                }
            }
        }
    }
}

// ---------------- layer 1 aggregation: one wave per node, ALL 8 heads; fp16 gathers ----------------
__global__ void __launch_bounds__(256) agg1_kernel(const __half* __restrict__ h_g, const float* __restrict__ ssrc,
                                                   const float* __restrict__ sdst,
                                                   const int* __restrict__ row_ptr, const int* __restrict__ sidx,
                                                   __half* __restrict__ hcat, int n){
    const int w = threadIdx.x >> 6, lane = threadIdx.x & 63;
    const int node = blockIdx.x*4 + w;
    if (node >= n) return;
    const int r0 = row_ptr[node], r1 = row_ptr[node+1];
    const int h = lane >> 3;                         // this lane's head (8 feats/lane)
    const float ssh = ssrc[(size_t)node*8 + h];
    float acc[8] = {};
    float wsum = 0.f;
    int e = r0;
    for (; e + 3 < r1; e += 4){
        int j0 = sidx[e], j1 = sidx[e+1], j2 = sidx[e+2], j3 = sidx[e+3];
        uint4 g0 = *(const uint4*)(h_g + (size_t)j0*512 + lane*8);
        uint4 g1 = *(const uint4*)(h_g + (size_t)j1*512 + lane*8);
        uint4 g2 = *(const uint4*)(h_g + (size_t)j2*512 + lane*8);
        uint4 g3 = *(const uint4*)(h_g + (size_t)j3*512 + lane*8);
        float s0 = sdst[(size_t)j0*8 + h], s1 = sdst[(size_t)j1*8 + h];
        float s2 = sdst[(size_t)j2*8 + h], s3 = sdst[(size_t)j3*8 + h];
        float w0 = __expf(lrelu(ssh + s0));
        float w1 = __expf(lrelu(ssh + s1));
        float w2 = __expf(lrelu(ssh + s2));
        float w3 = __expf(lrelu(ssh + s3));
        const unsigned int* u0 = &g0.x; const unsigned int* u1 = &g1.x;
        const unsigned int* u2 = &g2.x; const unsigned int* u3 = &g3.x;
        #pragma unroll
        for (int q = 0; q < 4; ++q){
            float2 f0 = __half22float2(*(const __half2*)&u0[q]);
            float2 f1 = __half22float2(*(const __half2*)&u1[q]);
            float2 f2 = __half22float2(*(const __half2*)&u2[q]);
            float2 f3 = __half22float2(*(const __half2*)&u3[q]);
            acc[2*q]   += w0*f0.x + w1*f1.x + w2*f2.x + w3*f3.x;
            acc[2*q+1] += w0*f0.y + w1*f1.y + w2*f2.y + w3*f3.y;
        }
        wsum += (w0 + w1) + (w2 + w3);
    }
    for (; e < r1; ++e){
        int j = sidx[e];
        uint4 g = *(const uint4*)(h_g + (size_t)j*512 + lane*8);
        float wg = __expf(lrelu(ssh + sdst[(size_t)j*8 + h]));
        const unsigned int* u = &g.x;
        #pragma unroll
        for (int q = 0; q < 4; ++q){
            float2 f = __half22float2(*(const __half2*)&u[q]);
            acc[2*q]   += wg*f.x;
            acc[2*q+1] += wg*f.y;
        }
        wsum += wg;
    }
    float inv = 1.f / wsum;
    union { uint4 u; __half hv[8]; } pk;
    #pragma unroll
    for (int q = 0; q < 8; ++q) pk.hv[q] = __float2half(elu_f(acc[q]*inv));
    *(uint4*)(hcat + (size_t)node*512 + lane*8) = pk.u;
}

// ---------------- layer 2 GEMM (+ scores fused): hcat(fp16)[n,512] @ W2[512,20] ----------------
__global__ void __launch_bounds__(256) gemm2_kernel(const __half* __restrict__ hcat, const float* __restrict__ W2,
                                                    const float* __restrict__ a2,
                                                    float* __restrict__ h2, float* __restrict__ ssrc,
                                                    float* __restrict__ sdst, int n){
    __shared__ float As[16][257];
    __shared__ float Ws[16][20];
    const int tid = threadIdx.x;
    const int node = blockIdx.x*256 + tid;
    float acc[20] = {};
    for (int k0 = 0; k0 < 512; k0 += 16){
        uint4 u0 = {0,0,0,0}, u1 = {0,0,0,0};
        if (node < n){
            const __half* src = hcat + (size_t)node*512 + k0;
            u0 = *(const uint4*)src;
            u1 = *(const uint4*)(src + 8);
        }
        const unsigned int* ua = &u0.x;
        const unsigned int* ub = &u1.x;
        #pragma unroll
        for (int q = 0; q < 4; ++q){
            float2 f = __half22float2(*(const __half2*)&ua[q]);
            As[2*q][tid] = f.x; As[2*q+1][tid] = f.y;
            float2 g = __half22float2(*(const __half2*)&ub[q]);
            As[8+2*q][tid] = g.x; As[8+2*q+1][tid] = g.y;
        }
        for (int q = tid; q < 320; q += 256){
            int kr = q/20, cc = q%20;
            Ws[kr][cc] = W2[(size_t)(k0 + kr)*20 + cc];
        }
        __syncthreads();
        #pragma unroll
        for (int kk = 0; kk < 16; ++kk){
            float a = As[kk][tid];
            #pragma unroll
            for (int cc = 0; cc < 20; ++cc) acc[cc] += a*Ws[kk][cc];
        }
        __syncthreads();
    }
    if (node < n){
        float s0 = 0.f, s1 = 0.f;
        #pragma unroll
        for (int cc = 0; cc < 20; ++cc){
            h2[(size_t)node*20 + cc] = acc[cc];
            s0 += acc[cc]*a2[cc];
            s1 += acc[cc]*a2[20 + cc];
        }
        ssrc[node] = s0; sdst[node] = s1;
    }
}

// ---------------- layer 2 aggregation ----------------
__global__ void __launch_bounds__(256) agg2_kernel(const float* __restrict__ h2, const float* __restrict__ ssrc,
                                                   const float* __restrict__ sdstv,
                                                   const int* __restrict__ row_ptr, const int* __restrict__ sidx,
                                                   float* __restrict__ out, int n){
    const int w = threadIdx.x >> 6, lane = threadIdx.x & 63;
    const int node = blockIdx.x*4 + w;
    if (node >= n) return;
    const int r0 = row_ptr[node], r1 = row_ptr[node+1];
    const float ss = ssrc[node];
    const bool act = lane < 20;
    float acc = 0.f, wsum = 0.f;
    int e = r0;
    for (; e + 3 < r1; e += 4){
        int j0 = sidx[e], j1 = sidx[e+1], j2 = sidx[e+2], j3 = sidx[e+3];
        float v0 = act ? h2[(size_t)j0*20 + lane] : 0.f;
        float v1 = act ? h2[(size_t)j1*20 + lane] : 0.f;
        float v2 = act ? h2[(size_t)j2*20 + lane] : 0.f;
        float v3 = act ? h2[(size_t)j3*20 + lane] : 0.f;
        float s0 = sdstv[j0], s1 = sdstv[j1], s2 = sdstv[j2], s3 = sdstv[j3];
        float w0 = __expf(lrelu(ss + s0));
        float w1 = __expf(lrelu(ss + s1));
        float w2 = __expf(lrelu(ss + s2));
        float w3 = __expf(lrelu(ss + s3));
        acc += w0*v0 + w1*v1 + w2*v2 + w3*v3;
        wsum += (w0 + w1) + (w2 + w3);
    }
    for (; e < r1; ++e){
        int j = sidx[e];
        float v = act ? h2[(size_t)j*20 + lane] : 0.f;
        float wg = __expf(lrelu(ss + sdstv[j]));
        acc += wg*v; wsum += wg;
    }
    if (act) out[(size_t)node*20 + lane] = elu_f(acc / wsum);
}

extern "C" void kernel_launch(void* const* d_in, const int* in_sizes, int n_in,
                              void* d_out, int out_size, void* d_ws, size_t ws_size,
                              hipStream_t stream){
    const float* x  = (const float*)d_in[0];
    const float* W1 = (const float*)d_in[1];
    const float* a1 = (const float*)d_in[2];
    const float* W2 = (const float*)d_in[3];
    const float* a2 = (const float*)d_in[4];
    const int*   ei = (const int*)d_in[5];
    const int n = in_sizes[0] / 512;
    const int E = in_sizes[5] / 2;
    const int* e0 = ei;
    const int* e1 = ei + E;

    char* p = (char*)d_ws;
    auto alloc = [&](size_t bytes)->char*{ char* r = p; p += (bytes + 255) & ~(size_t)255; return r; };
    // bufA holds x_hi during gemm1, then is reused as hcat (gemm1 completes before agg1 writes hcat)
    unsigned short* xhi  = (unsigned short*)alloc((size_t)n*512*2);   // 51.2 MB (-> hcat)
    unsigned short* xlo  = (unsigned short*)alloc((size_t)n*512*2);   // 51.2 MB (-> h2/scores2 after gemm1)
    __half*         h_g  = (__half*)        alloc((size_t)n*512*2);   // 51.2 MB
    unsigned short* wThi = (unsigned short*)alloc((size_t)8*64*512*2);
    unsigned short* wTlo = (unsigned short*)alloc((size_t)8*64*512*2);
    float* ssrc1   = (float*)alloc((size_t)n*8*4);
    float* sdst1   = (float*)alloc((size_t)n*8*4);
    int*   cnt     = (int*)  alloc((size_t)n*4);
    int*   row_ptr = (int*)  alloc(((size_t)n + 1)*4);
    int*   cursor  = (int*)  alloc((size_t)n*4);
    int*   sidx    = (int*)  alloc((size_t)E*4);
    // aliases (dead buffers reused)
    __half* hcat  = (__half*)xhi;            // written by agg1, after gemm1 stops reading xhi
    float*  h2    = (float*)xlo;             // written by gemm2, after gemm1 stops reading xlo
    float*  ssrc2 = h2 + (size_t)n*20;
    float*  sdst2 = ssrc2 + n;

    // CSR by e0, XCD-sliced
    hipMemsetAsync(cnt, 0, (size_t)n*4, stream);
    const int KCH = 192;
    hist_sliced_kernel   <<<KCH*8, 256, 0, stream>>>(e0, E, n, cnt);
    scan_kernel          <<<1, 1024, 0, stream>>>(cnt, n, row_ptr, cursor);
    scatter_sliced_kernel<<<KCH*8, 256, 0, stream>>>(e0, e1, E, n, cursor, sidx);

    // prep
    const int total4 = n*512/4;
    split_x_kernel<<<(total4 + 255)/256, 256, 0, stream>>>(x, xhi, xlo, total4);
    prep_w_kernel <<<1024, 256, 0, stream>>>(W1, wThi, wTlo);

    // layer 1
    const int mb = (n + 127)/128;
    gemm1_mfma_kernel<<<dim3(mb, 4), 256, 0, stream>>>(xhi, xlo, wThi, wTlo, a1, h_g, ssrc1, sdst1, n);
    agg1_kernel      <<<(n + 3)/4,   256, 0, stream>>>(h_g, ssrc1, sdst1, row_ptr, sidx, hcat, n);

    // layer 2
    const int nb256 = (n + 255)/256;
    gemm2_kernel<<<nb256, 256, 0, stream>>>(hcat, W2, a2, h2, ssrc2, sdst2, n);
    agg2_kernel <<<(n + 3)/4, 256, 0, stream>>>(h2, ssrc2, sdst2, row_ptr, sidx, (float*)d_out, n);
}

// Round 5
// 869.807 us; speedup vs baseline: 2.5473x; 1.1813x over previous
//
#include <hip/hip_runtime.h>
#include <hip/hip_fp16.h>
#include <math.h>

#define SLOPE 0.2f

typedef short bf16x8 __attribute__((ext_vector_type(8)));
typedef float f32x4  __attribute__((ext_vector_type(4)));

static __device__ __forceinline__ float elu_f(float x){ return x > 0.f ? x : (__expf(x) - 1.f); }
static __device__ __forceinline__ float lrelu(float t){ return t > 0.f ? t : SLOPE*t; }
static __device__ __forceinline__ unsigned short f2bf_rne(float f){
    unsigned int u = __float_as_uint(f);
    unsigned int r = (u + 0x7FFFu + ((u >> 16) & 1u)) >> 16;
    return (unsigned short)r;
}
static __device__ __forceinline__ float bf2f(unsigned short h){ return __uint_as_float(((unsigned int)h) << 16); }

#define ASYNC_COPY16(gp, lp) \
    __builtin_amdgcn_global_load_lds((const __attribute__((address_space(1))) void*)(gp), \
                                     (__attribute__((address_space(3))) void*)(lp), 16, 0, 0)

// ---------------- CSR build (XCD-sliced) ----------------
__global__ void __launch_bounds__(256) hist_sliced_kernel(const int* __restrict__ e0, int E, int n,
                                                          int* __restrict__ cnt){
    const int s = blockIdx.x & 7;
    const int c = blockIdx.x >> 3;
    const int K = gridDim.x >> 3;
    const int lo = (int)((long)s*n >> 3), hi = (int)((long)(s+1)*n >> 3);
    const int i0 = (int)((long)c*E/K), i1 = (int)((long)(c+1)*E/K);
    for (int i = i0 + threadIdx.x; i < i1; i += 256){
        int j = e0[i];
        if (j >= lo && j < hi) atomicAdd(&cnt[j], 1);
    }
}

__global__ void __launch_bounds__(1024) scan_kernel(const int* __restrict__ cnt, int n,
                                                    int* __restrict__ row_ptr, int* __restrict__ cursor){
    __shared__ int wtot[16];
    __shared__ int carry_sh;
    if (threadIdx.x == 0) carry_sh = 0;
    __syncthreads();
    const int lane = threadIdx.x & 63, wid = threadIdx.x >> 6;
    const int nch = (n + 1023) >> 10;
    for (int c = 0; c < nch; ++c){
        int i = (c << 10) + threadIdx.x;
        int v = (i < n) ? cnt[i] : 0;
        int val = v;
        #pragma unroll
        for (int off = 1; off < 64; off <<= 1){
            int t = __shfl_up(val, off, 64);
            if (lane >= off) val += t;
        }
        if (lane == 63) wtot[wid] = val;
        __syncthreads();
        int tot = 0, wexcl = 0;
        #pragma unroll
        for (int w = 0; w < 16; ++w){ int t = wtot[w]; tot += t; if (w < wid) wexcl += t; }
        int excl = carry_sh + wexcl + (val - v);
        if (i < n){ row_ptr[i] = excl; cursor[i] = excl; }
        __syncthreads();
        if (threadIdx.x == 0) carry_sh += tot;
        __syncthreads();
    }
    if (threadIdx.x == 0) row_ptr[n] = carry_sh;
}

__global__ void __launch_bounds__(256) scatter_sliced_kernel(const int* __restrict__ e0, const int* __restrict__ e1,
                                                             int E, int n,
                                                             int* __restrict__ cursor, int* __restrict__ sidx){
    const int s = blockIdx.x & 7;
    const int c = blockIdx.x >> 3;
    const int K = gridDim.x >> 3;
    const int lo = (int)((long)s*n >> 3), hi = (int)((long)(s+1)*n >> 3);
    const int i0 = (int)((long)c*E/K), i1 = (int)((long)(c+1)*E/K);
    for (int i = i0 + threadIdx.x; i < i1; i += 256){
        int j = e0[i];
        if (j >= lo && j < hi){
            int p = atomicAdd(&cursor[j], 1);
            sidx[p] = e1[i];
        }
    }
}

// ---------------- prep: split x into bf16 hi/lo ----------------
__global__ void __launch_bounds__(256) split_x_kernel(const float* __restrict__ x,
                                                      unsigned short* __restrict__ xhi,
                                                      unsigned short* __restrict__ xlo, int total4){
    int i = blockIdx.x*256 + threadIdx.x;
    if (i >= total4) return;
    float4 v = ((const float4*)x)[i];
    ushort4 h, l;
    h.x = f2bf_rne(v.x); l.x = f2bf_rne(v.x - bf2f(h.x));
    h.y = f2bf_rne(v.y); l.y = f2bf_rne(v.y - bf2f(h.y));
    h.z = f2bf_rne(v.z); l.z = f2bf_rne(v.z - bf2f(h.z));
    h.w = f2bf_rne(v.w); l.w = f2bf_rne(v.w - bf2f(h.w));
    ((ushort4*)xhi)[i] = h;
    ((ushort4*)xlo)[i] = l;
}

// ---------------- prep: transpose W1 [8][512][64] -> wT [512 cols][512 k] bf16 hi/lo (col = head*64+f) ----------------
__global__ void __launch_bounds__(256) prep_w_kernel(const float* __restrict__ W1,
                                                     unsigned short* __restrict__ wThi,
                                                     unsigned short* __restrict__ wTlo){
    int idx = blockIdx.x*256 + threadIdx.x;          // 8*64*512 = 262144
    int head = idx >> 15, rem = idx & 32767;
    int c = rem >> 9, k = rem & 511;
    float f = W1[((size_t)head << 15) + k*64 + c];
    unsigned short h = f2bf_rne(f);
    wThi[idx] = h;
    wTlo[idx] = f2bf_rne(f - bf2f(h));
}

// ---------------- layer 1: LDS-staged split-bf16 MFMA GEMM + fused scores ----------------
// One dispatch, all 8 heads. C[50000 x 512] = x @ Wcat. 128x128 tile, BK=32, 4 waves (2x2).
// Wave covers 64 rows x 64 cols = exactly one head's features. acc = hi*hi + hi*lo + lo*hi.
__global__ void __launch_bounds__(256) gemm1_mfma_kernel(const unsigned short* __restrict__ xhi,
                                                         const unsigned short* __restrict__ xlo,
                                                         const unsigned short* __restrict__ wThi,
                                                         const unsigned short* __restrict__ wTlo,
                                                         const float* __restrict__ a1,
                                                         __half* __restrict__ h_g,
                                                         float* __restrict__ ssrc, float* __restrict__ sdst,
                                                         int n, int nwg){
    __shared__ unsigned short lds[16384];   // 32 KB: Ahi | Alo | Bhi | Blo, each [128][32] bf16
    // bijective XCD swizzle (m204): same-rowtile col-tiles land on one XCD -> A slab fetched once
    const int bid = blockIdx.x;
    const int xcd = bid & 7, jj = bid >> 3;
    const int q = nwg >> 3, r = nwg & 7;
    const int logical = (xcd < r ? xcd*(q+1) : r*(q+1) + (xcd-r)*q) + jj;
    const int rowtile = logical >> 2, ct = logical & 3;
    const int row0 = rowtile*128, col0 = ct*128;
    const int w = threadIdx.x >> 6, lane = threadIdx.x & 63;
    const int wm = w >> 1, wn = w & 1;
    const int lr = lane & 15, lk = lane >> 4;
    f32x4 acc[4][4] = {};
    // staging map: wave w stages LDS bytes [w*8192,(w+1)*8192) as 8 x 1KB global_load_lds
    const unsigned short* sbase[8];
    unsigned int soff[8];
    #pragma unroll
    for (int i = 0; i < 8; ++i){
        unsigned int off = w*8192u + i*1024u + lane*16u;   // byte offset into lds
        unsigned int arr = off >> 13, within = off & 8191u;
        unsigned int rrow = within >> 6, kel = (within & 63u) >> 1;
        const unsigned short* g;
        size_t gidx;
        if (arr == 0)      { g = xhi;  gidx = (size_t)(row0 + rrow)*512 + kel; }
        else if (arr == 1) { g = xlo;  gidx = (size_t)(row0 + rrow)*512 + kel; }
        else if (arr == 2) { g = wThi; gidx = (size_t)(col0 + rrow)*512 + kel; }
        else               { g = wTlo; gidx = (size_t)(col0 + rrow)*512 + kel; }
        sbase[i] = g + gidx;
        soff[i] = (w*8192u + i*1024u);                      // wave-uniform LDS base for this load
    }
    const unsigned short* Ahi = lds;
    const unsigned short* Alo = lds + 4096;
    const unsigned short* Bhi = lds + 8192;
    const unsigned short* Blo = lds + 12288;
    for (int k0 = 0; k0 < 512; k0 += 32){
        #pragma unroll
        for (int i = 0; i < 8; ++i)
            ASYNC_COPY16(sbase[i] + k0, (char*)lds + soff[i]);
        __syncthreads();                                    // drain vmcnt + barrier
        bf16x8 a_h[4], a_l[4], b_h[4], b_l[4];
        #pragma unroll
        for (int mi = 0; mi < 4; ++mi){
            int rowl = wm*64 + mi*16 + lr;
            a_h[mi] = *(const bf16x8*)(Ahi + rowl*32 + lk*8);
            a_l[mi] = *(const bf16x8*)(Alo + rowl*32 + lk*8);
        }
        #pragma unroll
        for (int ni = 0; ni < 4; ++ni){
            int coll = wn*64 + ni*16 + lr;
            b_h[ni] = *(const bf16x8*)(Bhi + coll*32 + lk*8);
            b_l[ni] = *(const bf16x8*)(Blo + coll*32 + lk*8);
        }
        #pragma unroll
        for (int mi = 0; mi < 4; ++mi)
            #pragma unroll
            for (int ni = 0; ni < 4; ++ni){
                f32x4& A = acc[mi][ni];
                A = __builtin_amdgcn_mfma_f32_16x16x32_bf16(a_h[mi], b_h[ni], A, 0, 0, 0);
                A = __builtin_amdgcn_mfma_f32_16x16x32_bf16(a_h[mi], b_l[ni], A, 0, 0, 0);
                A = __builtin_amdgcn_mfma_f32_16x16x32_bf16(a_l[mi], b_h[ni], A, 0, 0, 0);
            }
        __syncthreads();                                    // all reads done before next overwrite
    }
    // epilogue: head = ct*2 + wn; C layout: col = ni*16+lr, row = mi*16 + lk*4 + reg
    const int head = ct*2 + wn;
    float as_[4], ad_[4];
    #pragma unroll
    for (int ni = 0; ni < 4; ++ni){
        as_[ni] = a1[(size_t)head*128 + ni*16 + lr];
        ad_[ni] = a1[(size_t)head*128 + 64 + ni*16 + lr];
    }
    #pragma unroll
    for (int mi = 0; mi < 4; ++mi){
        #pragma unroll
        for (int reg = 0; reg < 4; ++reg){
            float s = 0.f, d = 0.f;
            #pragma unroll
            for (int ni = 0; ni < 4; ++ni){
                float v = acc[mi][ni][reg];
                s += v*as_[ni]; d += v*ad_[ni];
            }
            s += __shfl_xor(s, 1); d += __shfl_xor(d, 1);
            s += __shfl_xor(s, 2); d += __shfl_xor(d, 2);
            s += __shfl_xor(s, 4); d += __shfl_xor(d, 4);
            s += __shfl_xor(s, 8); d += __shfl_xor(d, 8);
            const int node = row0 + wm*64 + mi*16 + lk*4 + reg;
            if (node < n){
                #pragma unroll
                for (int ni = 0; ni < 4; ++ni)
                    h_g[(size_t)node*512 + head*64 + ni*16 + lr] = __float2half(acc[mi][ni][reg]);
                if (lr == 0){
                    ssrc[(size_t)node*8 + head] = s;
                    sdst[(size_t)node*8 + head] = d;
                }
            }
        }
    }
}

// ---------------- layer 1 aggregation: one wave per node, ALL 8 heads; fp16 gathers ----------------
__global__ void __launch_bounds__(256) agg1_kernel(const __half* __restrict__ h_g, const float* __restrict__ ssrc,
                                                   const float* __restrict__ sdst,
                                                   const int* __restrict__ row_ptr, const int* __restrict__ sidx,
                                                   __half* __restrict__ hcat, int n){
    const int w = threadIdx.x >> 6, lane = threadIdx.x & 63;
    const int node = blockIdx.x*4 + w;
    if (node >= n) return;
    const int r0 = row_ptr[node], r1 = row_ptr[node+1];
    const int h = lane >> 3;                         // this lane's head (8 feats/lane)
    const float ssh = ssrc[(size_t)node*8 + h];
    float acc[8] = {};
    float wsum = 0.f;
    int e = r0;
    for (; e + 3 < r1; e += 4){
        int j0 = sidx[e], j1 = sidx[e+1], j2 = sidx[e+2], j3 = sidx[e+3];
        uint4 g0 = *(const uint4*)(h_g + (size_t)j0*512 + lane*8);
        uint4 g1 = *(const uint4*)(h_g + (size_t)j1*512 + lane*8);
        uint4 g2 = *(const uint4*)(h_g + (size_t)j2*512 + lane*8);
        uint4 g3 = *(const uint4*)(h_g + (size_t)j3*512 + lane*8);
        float s0 = sdst[(size_t)j0*8 + h], s1 = sdst[(size_t)j1*8 + h];
        float s2 = sdst[(size_t)j2*8 + h], s3 = sdst[(size_t)j3*8 + h];
        float w0 = __expf(lrelu(ssh + s0));
        float w1 = __expf(lrelu(ssh + s1));
        float w2 = __expf(lrelu(ssh + s2));
        float w3 = __expf(lrelu(ssh + s3));
        const unsigned int* u0 = &g0.x; const unsigned int* u1 = &g1.x;
        const unsigned int* u2 = &g2.x; const unsigned int* u3 = &g3.x;
        #pragma unroll
        for (int q = 0; q < 4; ++q){
            float2 f0 = __half22float2(*(const __half2*)&u0[q]);
            float2 f1 = __half22float2(*(const __half2*)&u1[q]);
            float2 f2 = __half22float2(*(const __half2*)&u2[q]);
            float2 f3 = __half22float2(*(const __half2*)&u3[q]);
            acc[2*q]   += w0*f0.x + w1*f1.x + w2*f2.x + w3*f3.x;
            acc[2*q+1] += w0*f0.y + w1*f1.y + w2*f2.y + w3*f3.y;
        }
        wsum += (w0 + w1) + (w2 + w3);
    }
    for (; e < r1; ++e){
        int j = sidx[e];
        uint4 g = *(const uint4*)(h_g + (size_t)j*512 + lane*8);
        float wg = __expf(lrelu(ssh + sdst[(size_t)j*8 + h]));
        const unsigned int* u = &g.x;
        #pragma unroll
        for (int q = 0; q < 4; ++q){
            float2 f = __half22float2(*(const __half2*)&u[q]);
            acc[2*q]   += wg*f.x;
            acc[2*q+1] += wg*f.y;
        }
        wsum += wg;
    }
    float inv = 1.f / wsum;
    union { uint4 u; __half hv[8]; } pk;
    #pragma unroll
    for (int q = 0; q < 8; ++q) pk.hv[q] = __float2half(elu_f(acc[q]*inv));
    *(uint4*)(hcat + (size_t)node*512 + lane*8) = pk.u;
}

// ---------------- layer 2 GEMM (+ scores fused): hcat(fp16)[n,512] @ W2[512,20] ----------------
__global__ void __launch_bounds__(256) gemm2_kernel(const __half* __restrict__ hcat, const float* __restrict__ W2,
                                                    const float* __restrict__ a2,
                                                    float* __restrict__ h2, float* __restrict__ ssrc,
                                                    float* __restrict__ sdst, int n){
    __shared__ float As[16][257];
    __shared__ float Ws[16][20];
    const int tid = threadIdx.x;
    const int node = blockIdx.x*256 + tid;
    float acc[20] = {};
    for (int k0 = 0; k0 < 512; k0 += 16){
        uint4 u0 = {0,0,0,0}, u1 = {0,0,0,0};
        if (node < n){
            const __half* src = hcat + (size_t)node*512 + k0;
            u0 = *(const uint4*)src;
            u1 = *(const uint4*)(src + 8);
        }
        const unsigned int* ua = &u0.x;
        const unsigned int* ub = &u1.x;
        #pragma unroll
        for (int q = 0; q < 4; ++q){
            float2 f = __half22float2(*(const __half2*)&ua[q]);
            As[2*q][tid] = f.x; As[2*q+1][tid] = f.y;
            float2 g = __half22float2(*(const __half2*)&ub[q]);
            As[8+2*q][tid] = g.x; As[8+2*q+1][tid] = g.y;
        }
        for (int q = tid; q < 320; q += 256){
            int kr = q/20, cc = q%20;
            Ws[kr][cc] = W2[(size_t)(k0 + kr)*20 + cc];
        }
        __syncthreads();
        #pragma unroll
        for (int kk = 0; kk < 16; ++kk){
            float a = As[kk][tid];
            #pragma unroll
            for (int cc = 0; cc < 20; ++cc) acc[cc] += a*Ws[kk][cc];
        }
        __syncthreads();
    }
    if (node < n){
        float s0 = 0.f, s1 = 0.f;
        #pragma unroll
        for (int cc = 0; cc < 20; ++cc){
            h2[(size_t)node*20 + cc] = acc[cc];
            s0 += acc[cc]*a2[cc];
            s1 += acc[cc]*a2[20 + cc];
        }
        ssrc[node] = s0; sdst[node] = s1;
    }
}

// ---------------- layer 2 aggregation ----------------
__global__ void __launch_bounds__(256) agg2_kernel(const float* __restrict__ h2, const float* __restrict__ ssrc,
                                                   const float* __restrict__ sdstv,
                                                   const int* __restrict__ row_ptr, const int* __restrict__ sidx,
                                                   float* __restrict__ out, int n){
    const int w = threadIdx.x >> 6, lane = threadIdx.x & 63;
    const int node = blockIdx.x*4 + w;
    if (node >= n) return;
    const int r0 = row_ptr[node], r1 = row_ptr[node+1];
    const float ss = ssrc[node];
    const bool act = lane < 20;
    float acc = 0.f, wsum = 0.f;
    int e = r0;
    for (; e + 3 < r1; e += 4){
        int j0 = sidx[e], j1 = sidx[e+1], j2 = sidx[e+2], j3 = sidx[e+3];
        float v0 = act ? h2[(size_t)j0*20 + lane] : 0.f;
        float v1 = act ? h2[(size_t)j1*20 + lane] : 0.f;
        float v2 = act ? h2[(size_t)j2*20 + lane] : 0.f;
        float v3 = act ? h2[(size_t)j3*20 + lane] : 0.f;
        float s0 = sdstv[j0], s1 = sdstv[j1], s2 = sdstv[j2], s3 = sdstv[j3];
        float w0 = __expf(lrelu(ss + s0));
        float w1 = __expf(lrelu(ss + s1));
        float w2 = __expf(lrelu(ss + s2));
        float w3 = __expf(lrelu(ss + s3));
        acc += w0*v0 + w1*v1 + w2*v2 + w3*v3;
        wsum += (w0 + w1) + (w2 + w3);
    }
    for (; e < r1; ++e){
        int j = sidx[e];
        float v = act ? h2[(size_t)j*20 + lane] : 0.f;
        float wg = __expf(lrelu(ss + sdstv[j]));
        acc += wg*v; wsum += wg;
    }
    if (act) out[(size_t)node*20 + lane] = elu_f(acc / wsum);
}

extern "C" void kernel_launch(void* const* d_in, const int* in_sizes, int n_in,
                              void* d_out, int out_size, void* d_ws, size_t ws_size,
                              hipStream_t stream){
    const float* x  = (const float*)d_in[0];
    const float* W1 = (const float*)d_in[1];
    const float* a1 = (const float*)d_in[2];
    const float* W2 = (const float*)d_in[3];
    const float* a2 = (const float*)d_in[4];
    const int*   ei = (const int*)d_in[5];
    const int n = in_sizes[0] / 512;
    const int E = in_sizes[5] / 2;
    const int* e0 = ei;
    const int* e1 = ei + E;

    char* p = (char*)d_ws;
    auto alloc = [&](size_t bytes)->char*{ char* r = p; p += (bytes + 255) & ~(size_t)255; return r; };
    unsigned short* xhi  = (unsigned short*)alloc((size_t)n*512*2);   // 51.2 MB (-> hcat)
    unsigned short* xlo  = (unsigned short*)alloc((size_t)n*512*2);   // 51.2 MB (-> h2/scores2)
    __half*         h_g  = (__half*)        alloc((size_t)n*512*2);   // 51.2 MB
    unsigned short* wThi = (unsigned short*)alloc((size_t)8*64*512*2);
    unsigned short* wTlo = (unsigned short*)alloc((size_t)8*64*512*2);
    float* ssrc1   = (float*)alloc((size_t)n*8*4);
    float* sdst1   = (float*)alloc((size_t)n*8*4);
    int*   cnt     = (int*)  alloc((size_t)n*4);
    int*   row_ptr = (int*)  alloc(((size_t)n + 1)*4);
    int*   cursor  = (int*)  alloc((size_t)n*4);
    int*   sidx    = (int*)  alloc((size_t)E*4);
    // aliases (dead buffers reused)
    __half* hcat  = (__half*)xhi;            // written by agg1, after gemm1 stops reading xhi
    float*  h2    = (float*)xlo;             // written by gemm2, after gemm1 stops reading xlo
    float*  ssrc2 = h2 + (size_t)n*20;
    float*  sdst2 = ssrc2 + n;

    // CSR by e0, XCD-sliced
    hipMemsetAsync(cnt, 0, (size_t)n*4, stream);
    const int KCH = 192;
    hist_sliced_kernel   <<<KCH*8, 256, 0, stream>>>(e0, E, n, cnt);
    scan_kernel          <<<1, 1024, 0, stream>>>(cnt, n, row_ptr, cursor);
    scatter_sliced_kernel<<<KCH*8, 256, 0, stream>>>(e0, e1, E, n, cursor, sidx);

    // prep
    const int total4 = n*512/4;
    split_x_kernel<<<(total4 + 255)/256, 256, 0, stream>>>(x, xhi, xlo, total4);
    prep_w_kernel <<<1024, 256, 0, stream>>>(W1, wThi, wTlo);

    // layer 1
    const int mb = (n + 127)/128;
    const int nwg = mb*4;
    gemm1_mfma_kernel<<<nwg, 256, 0, stream>>>(xhi, xlo, wThi, wTlo, a1, h_g, ssrc1, sdst1, n, nwg);
    agg1_kernel      <<<(n + 3)/4, 256, 0, stream>>>(h_g, ssrc1, sdst1, row_ptr, sidx, hcat, n);

    // layer 2
    const int nb256 = (n + 255)/256;
    gemm2_kernel<<<nb256, 256, 0, stream>>>(hcat, W2, a2, h2, ssrc2, sdst2, n);
    agg2_kernel <<<(n + 3)/4, 256, 0, stream>>>(h2, ssrc2, sdst2, row_ptr, sidx, (float*)d_out, n);
}

// Round 6
// 835.336 us; speedup vs baseline: 2.6524x; 1.0413x over previous
//
#include <hip/hip_runtime.h>
#include <hip/hip_fp16.h>
#include <math.h>

#define SLOPE 0.2f
#define SSHIFT 11               // source-slice = j >> 11 (2048 rows = 2 MB of h_g, fits one XCD L2)

typedef short bf16x8 __attribute__((ext_vector_type(8)));
typedef float f32x4  __attribute__((ext_vector_type(4)));

static __device__ __forceinline__ float elu_f(float x){ return x > 0.f ? x : (__expf(x) - 1.f); }
static __device__ __forceinline__ float lrelu(float t){ return t > 0.f ? t : SLOPE*t; }
static __device__ __forceinline__ unsigned short f2bf_rne(float f){
    unsigned int u = __float_as_uint(f);
    unsigned int r = (u + 0x7FFFu + ((u >> 16) & 1u)) >> 16;
    return (unsigned short)r;
}
static __device__ __forceinline__ float bf2f(unsigned short h){ return __uint_as_float(((unsigned int)h) << 16); }

#define ASYNC_COPY16(gp, lp) \
    __builtin_amdgcn_global_load_lds((const __attribute__((address_space(1))) void*)(gp), \
                                     (__attribute__((address_space(3))) void*)(lp), 16, 0, 0)

// ---------------- CSR build, bucketed by (dst, src-slice); XCD-sliced by dst ----------------
__global__ void __launch_bounds__(256) hist_sliced_kernel(const int* __restrict__ e0, const int* __restrict__ e1,
                                                          int E, int n, int NS, int* __restrict__ cnt){
    const int s = blockIdx.x & 7;
    const int c = blockIdx.x >> 3;
    const int K = gridDim.x >> 3;
    const int lo = (int)((long)s*n >> 3), hi = (int)((long)(s+1)*n >> 3);
    const int i0 = (int)((long)c*E/K), i1 = (int)((long)(c+1)*E/K);
    for (int i = i0 + threadIdx.x; i < i1; i += 256){
        int j = e0[i];
        if (j >= lo && j < hi) atomicAdd(&cnt[j*NS + (e1[i] >> SSHIFT)], 1);
    }
}

// hierarchical exclusive scan over T = n*NS cells: reduce -> small scan -> apply (in-place cnt->cursor)
__global__ void __launch_bounds__(256) scan_reduce_kernel(const int* __restrict__ cnt, int T, int* __restrict__ bsum){
    int c0 = blockIdx.x*4096 + threadIdx.x*16;
    int sum = 0;
    #pragma unroll
    for (int q = 0; q < 16; ++q){ int i = c0 + q; if (i < T) sum += cnt[i]; }
    #pragma unroll
    for (int off = 1; off < 64; off <<= 1) sum += __shfl_xor(sum, off, 64);
    __shared__ int ws_[4];
    int lane = threadIdx.x & 63, wid = threadIdx.x >> 6;
    if (lane == 0) ws_[wid] = sum;
    __syncthreads();
    if (threadIdx.x == 0) bsum[blockIdx.x] = ws_[0] + ws_[1] + ws_[2] + ws_[3];
}

__global__ void __launch_bounds__(512) scan_small_kernel(const int* __restrict__ bsum, int NB, int* __restrict__ bexcl){
    int t = threadIdx.x;
    int v = (t < NB) ? bsum[t] : 0;
    int lane = t & 63, wid = t >> 6;
    int val = v;
    #pragma unroll
    for (int off = 1; off < 64; off <<= 1){ int u = __shfl_up(val, off, 64); if (lane >= off) val += u; }
    __shared__ int wt[8];
    if (lane == 63) wt[wid] = val;
    __syncthreads();
    int base = 0;
    for (int w2 = 0; w2 < wid; ++w2) base += wt[w2];
    if (t < NB) bexcl[t] = base + val - v;
}

__global__ void __launch_bounds__(256) scan_apply_kernel(int* __restrict__ cnt_cur, int T,
                                                         const int* __restrict__ bexcl){
    int c0 = blockIdx.x*4096 + threadIdx.x*16;
    int v[16];
    #pragma unroll
    for (int q = 0; q < 16; ++q){ int i = c0 + q; v[q] = (i < T) ? cnt_cur[i] : 0; }
    int tsum = 0;
    #pragma unroll
    for (int q = 0; q < 16; ++q){ int t_ = v[q]; v[q] = tsum; tsum += t_; }
    int lane = threadIdx.x & 63, wid = threadIdx.x >> 6;
    int val = tsum;
    #pragma unroll
    for (int off = 1; off < 64; off <<= 1){ int u = __shfl_up(val, off, 64); if (lane >= off) val += u; }
    __shared__ int wt[4];
    if (lane == 63) wt[wid] = val;
    __syncthreads();
    int base = bexcl[blockIdx.x];
    for (int w2 = 0; w2 < wid; ++w2) base += wt[w2];
    base += val - tsum;
    #pragma unroll
    for (int q = 0; q < 16; ++q){ int i = c0 + q; if (i < T) cnt_cur[i] = base + v[q]; }
}

__global__ void __launch_bounds__(256) scatter_sliced_kernel(const int* __restrict__ e0, const int* __restrict__ e1,
                                                             int E, int n, int NS,
                                                             int* __restrict__ cursor, int* __restrict__ sidx){
    const int s = blockIdx.x & 7;
    const int c = blockIdx.x >> 3;
    const int K = gridDim.x >> 3;
    const int lo = (int)((long)s*n >> 3), hi = (int)((long)(s+1)*n >> 3);
    const int i0 = (int)((long)c*E/K), i1 = (int)((long)(c+1)*E/K);
    for (int i = i0 + threadIdx.x; i < i1; i += 256){
        int j = e0[i];
        if (j >= lo && j < hi){
            int jj = e1[i];
            int p = atomicAdd(&cursor[j*NS + (jj >> SSHIFT)], 1);
            sidx[p] = jj;
        }
    }
}

// ---------------- prep: split x into bf16 hi/lo ----------------
__global__ void __launch_bounds__(256) split_x_kernel(const float* __restrict__ x,
                                                      unsigned short* __restrict__ xhi,
                                                      unsigned short* __restrict__ xlo, int total4){
    int i = blockIdx.x*256 + threadIdx.x;
    if (i >= total4) return;
    float4 v = ((const float4*)x)[i];
    ushort4 h, l;
    h.x = f2bf_rne(v.x); l.x = f2bf_rne(v.x - bf2f(h.x));
    h.y = f2bf_rne(v.y); l.y = f2bf_rne(v.y - bf2f(h.y));
    h.z = f2bf_rne(v.z); l.z = f2bf_rne(v.z - bf2f(h.z));
    h.w = f2bf_rne(v.w); l.w = f2bf_rne(v.w - bf2f(h.w));
    ((ushort4*)xhi)[i] = h;
    ((ushort4*)xlo)[i] = l;
}

// ---------------- prep: W1 [8][512][64] -> wT [512 cols][512 k] bf16 hi/lo (col = head*64+f) ----------------
__global__ void __launch_bounds__(256) prep_w_kernel(const float* __restrict__ W1,
                                                     unsigned short* __restrict__ wThi,
                                                     unsigned short* __restrict__ wTlo){
    int idx = blockIdx.x*256 + threadIdx.x;          // 8*64*512 = 262144
    int head = idx >> 15, rem = idx & 32767;
    int c = rem >> 9, k = rem & 511;
    float f = W1[((size_t)head << 15) + k*64 + c];
    unsigned short h = f2bf_rne(f);
    wThi[idx] = h;
    wTlo[idx] = f2bf_rne(f - bf2f(h));
}

// ---------------- layer 1: LDS-staged split-bf16 MFMA GEMM + fused scores ----------------
__global__ void __launch_bounds__(256) gemm1_mfma_kernel(const unsigned short* __restrict__ xhi,
                                                         const unsigned short* __restrict__ xlo,
                                                         const unsigned short* __restrict__ wThi,
                                                         const unsigned short* __restrict__ wTlo,
                                                         const float* __restrict__ a1,
                                                         __half* __restrict__ h_g,
                                                         float* __restrict__ ssrc, float* __restrict__ sdst,
                                                         int n, int nwg){
    __shared__ unsigned short lds[16384];   // 32 KB: Ahi | Alo | Bhi | Blo, each [128][32] bf16
    const int bid = blockIdx.x;
    const int xcd = bid & 7, jj = bid >> 3;
    const int q = nwg >> 3, r = nwg & 7;
    const int logical = (xcd < r ? xcd*(q+1) : r*(q+1) + (xcd-r)*q) + jj;
    const int rowtile = logical >> 2, ct = logical & 3;
    const int row0 = rowtile*128, col0 = ct*128;
    const int w = threadIdx.x >> 6, lane = threadIdx.x & 63;
    const int wm = w >> 1, wn = w & 1;
    const int lr = lane & 15, lk = lane >> 4;
    f32x4 acc[4][4] = {};
    const unsigned short* sbase[8];
    unsigned int soff[8];
    #pragma unroll
    for (int i = 0; i < 8; ++i){
        unsigned int off = w*8192u + i*1024u + lane*16u;
        unsigned int arr = off >> 13, within = off & 8191u;
        unsigned int rrow = within >> 6, kel = (within & 63u) >> 1;
        const unsigned short* g;
        size_t gidx;
        if (arr == 0)      { g = xhi;  gidx = (size_t)(row0 + rrow)*512 + kel; }
        else if (arr == 1) { g = xlo;  gidx = (size_t)(row0 + rrow)*512 + kel; }
        else if (arr == 2) { g = wThi; gidx = (size_t)(col0 + rrow)*512 + kel; }
        else               { g = wTlo; gidx = (size_t)(col0 + rrow)*512 + kel; }
        sbase[i] = g + gidx;
        soff[i] = (w*8192u + i*1024u);
    }
    const unsigned short* Ahi = lds;
    const unsigned short* Alo = lds + 4096;
    const unsigned short* Bhi = lds + 8192;
    const unsigned short* Blo = lds + 12288;
    for (int k0 = 0; k0 < 512; k0 += 32){
        #pragma unroll
        for (int i = 0; i < 8; ++i)
            ASYNC_COPY16(sbase[i] + k0, (char*)lds + soff[i]);
        __syncthreads();
        bf16x8 a_h[4], a_l[4], b_h[4], b_l[4];
        #pragma unroll
        for (int mi = 0; mi < 4; ++mi){
            int rowl = wm*64 + mi*16 + lr;
            a_h[mi] = *(const bf16x8*)(Ahi + rowl*32 + lk*8);
            a_l[mi] = *(const bf16x8*)(Alo + rowl*32 + lk*8);
        }
        #pragma unroll
        for (int ni = 0; ni < 4; ++ni){
            int coll = wn*64 + ni*16 + lr;
            b_h[ni] = *(const bf16x8*)(Bhi + coll*32 + lk*8);
            b_l[ni] = *(const bf16x8*)(Blo + coll*32 + lk*8);
        }
        #pragma unroll
        for (int mi = 0; mi < 4; ++mi)
            #pragma unroll
            for (int ni = 0; ni < 4; ++ni){
                f32x4& A = acc[mi][ni];
                A = __builtin_amdgcn_mfma_f32_16x16x32_bf16(a_h[mi], b_h[ni], A, 0, 0, 0);
                A = __builtin_amdgcn_mfma_f32_16x16x32_bf16(a_h[mi], b_l[ni], A, 0, 0, 0);
                A = __builtin_amdgcn_mfma_f32_16x16x32_bf16(a_l[mi], b_h[ni], A, 0, 0, 0);
            }
        __syncthreads();
    }
    const int head = ct*2 + wn;
    float as_[4], ad_[4];
    #pragma unroll
    for (int ni = 0; ni < 4; ++ni){
        as_[ni] = a1[(size_t)head*128 + ni*16 + lr];
        ad_[ni] = a1[(size_t)head*128 + 64 + ni*16 + lr];
    }
    #pragma unroll
    for (int mi = 0; mi < 4; ++mi){
        #pragma unroll
        for (int reg = 0; reg < 4; ++reg){
            float s = 0.f, d = 0.f;
            #pragma unroll
            for (int ni = 0; ni < 4; ++ni){
                float v = acc[mi][ni][reg];
                s += v*as_[ni]; d += v*ad_[ni];
            }
            s += __shfl_xor(s, 1); d += __shfl_xor(d, 1);
            s += __shfl_xor(s, 2); d += __shfl_xor(d, 2);
            s += __shfl_xor(s, 4); d += __shfl_xor(d, 4);
            s += __shfl_xor(s, 8); d += __shfl_xor(d, 8);
            const int node = row0 + wm*64 + mi*16 + lk*4 + reg;
            if (node < n){
                #pragma unroll
                for (int ni = 0; ni < 4; ++ni)
                    h_g[(size_t)node*512 + head*64 + ni*16 + lr] = __float2half(acc[mi][ni][reg]);
                if (lr == 0){
                    ssrc[(size_t)node*8 + head] = s;
                    sdst[(size_t)node*8 + head] = d;
                }
            }
        }
    }
}

// ---------------- layer 1 aggregation: one wave per node, ALL 8 heads; fp16 gathers, j-bucketed ----------------
__global__ void __launch_bounds__(256) agg1_kernel(const __half* __restrict__ h_g, const float* __restrict__ ssrc,
                                                   const float* __restrict__ sdst,
                                                   const int* __restrict__ bend, const int* __restrict__ sidx,
                                                   __half* __restrict__ hcat, int n, int NS){
    const int w = threadIdx.x >> 6, lane = threadIdx.x & 63;
    const int node = blockIdx.x*4 + w;
    if (node >= n) return;
    const int r0 = node ? bend[(size_t)node*NS - 1] : 0;
    const int r1 = bend[(size_t)(node+1)*NS - 1];
    const int h = lane >> 3;
    const float ssh = ssrc[(size_t)node*8 + h];
    float acc[8] = {};
    float wsum = 0.f;
    int e = r0;
    for (; e + 3 < r1; e += 4){
        int j0 = sidx[e], j1 = sidx[e+1], j2 = sidx[e+2], j3 = sidx[e+3];
        uint4 g0 = *(const uint4*)(h_g + (size_t)j0*512 + lane*8);
        uint4 g1 = *(const uint4*)(h_g + (size_t)j1*512 + lane*8);
        uint4 g2 = *(const uint4*)(h_g + (size_t)j2*512 + lane*8);
        uint4 g3 = *(const uint4*)(h_g + (size_t)j3*512 + lane*8);
        float s0 = sdst[(size_t)j0*8 + h], s1 = sdst[(size_t)j1*8 + h];
        float s2 = sdst[(size_t)j2*8 + h], s3 = sdst[(size_t)j3*8 + h];
        float w0 = __expf(lrelu(ssh + s0));
        float w1 = __expf(lrelu(ssh + s1));
        float w2 = __expf(lrelu(ssh + s2));
        float w3 = __expf(lrelu(ssh + s3));
        const unsigned int* u0 = &g0.x; const unsigned int* u1 = &g1.x;
        const unsigned int* u2 = &g2.x; const unsigned int* u3 = &g3.x;
        #pragma unroll
        for (int qq = 0; qq < 4; ++qq){
            float2 f0 = __half22float2(*(const __half2*)&u0[qq]);
            float2 f1 = __half22float2(*(const __half2*)&u1[qq]);
            float2 f2 = __half22float2(*(const __half2*)&u2[qq]);
            float2 f3 = __half22float2(*(const __half2*)&u3[qq]);
            acc[2*qq]   += w0*f0.x + w1*f1.x + w2*f2.x + w3*f3.x;
            acc[2*qq+1] += w0*f0.y + w1*f1.y + w2*f2.y + w3*f3.y;
        }
        wsum += (w0 + w1) + (w2 + w3);
    }
    for (; e < r1; ++e){
        int j = sidx[e];
        uint4 g = *(const uint4*)(h_g + (size_t)j*512 + lane*8);
        float wg = __expf(lrelu(ssh + sdst[(size_t)j*8 + h]));
        const unsigned int* u = &g.x;
        #pragma unroll
        for (int qq = 0; qq < 4; ++qq){
            float2 f = __half22float2(*(const __half2*)&u[qq]);
            acc[2*qq]   += wg*f.x;
            acc[2*qq+1] += wg*f.y;
        }
        wsum += wg;
    }
    float inv = 1.f / wsum;
    union { uint4 u; __half hv[8]; } pk;
    #pragma unroll
    for (int qq = 0; qq < 8; ++qq) pk.hv[qq] = __float2half(elu_f(acc[qq]*inv));
    *(uint4*)(hcat + (size_t)node*512 + lane*8) = pk.u;
}

// ---------------- layer 2 GEMM (+ scores fused): hcat(fp16)[n,512] @ W2[512,20] ----------------
__global__ void __launch_bounds__(256) gemm2_kernel(const __half* __restrict__ hcat, const float* __restrict__ W2,
                                                    const float* __restrict__ a2,
                                                    float* __restrict__ h2, float* __restrict__ ssrc,
                                                    float* __restrict__ sdst, int n){
    __shared__ float As[16][257];
    __shared__ float Ws[16][20];
    const int tid = threadIdx.x;
    const int node = blockIdx.x*256 + tid;
    float acc[20] = {};
    for (int k0 = 0; k0 < 512; k0 += 16){
        uint4 u0 = {0,0,0,0}, u1 = {0,0,0,0};
        if (node < n){
            const __half* src = hcat + (size_t)node*512 + k0;
            u0 = *(const uint4*)src;
            u1 = *(const uint4*)(src + 8);
        }
        const unsigned int* ua = &u0.x;
        const unsigned int* ub = &u1.x;
        #pragma unroll
        for (int qq = 0; qq < 4; ++qq){
            float2 f = __half22float2(*(const __half2*)&ua[qq]);
            As[2*qq][tid] = f.x; As[2*qq+1][tid] = f.y;
            float2 g = __half22float2(*(const __half2*)&ub[qq]);
            As[8+2*qq][tid] = g.x; As[8+2*qq+1][tid] = g.y;
        }
        for (int qq = tid; qq < 320; qq += 256){
            int kr = qq/20, cc = qq%20;
            Ws[kr][cc] = W2[(size_t)(k0 + kr)*20 + cc];
        }
        __syncthreads();
        #pragma unroll
        for (int kk = 0; kk < 16; ++kk){
            float a = As[kk][tid];
            #pragma unroll
            for (int cc = 0; cc < 20; ++cc) acc[cc] += a*Ws[kk][cc];
        }
        __syncthreads();
    }
    if (node < n){
        float s0 = 0.f, s1 = 0.f;
        #pragma unroll
        for (int cc = 0; cc < 20; ++cc){
            h2[(size_t)node*20 + cc] = acc[cc];
            s0 += acc[cc]*a2[cc];
            s1 += acc[cc]*a2[20 + cc];
        }
        ssrc[node] = s0; sdst[node] = s1;
    }
}

// ---------------- layer 2 aggregation ----------------
__global__ void __launch_bounds__(256) agg2_kernel(const float* __restrict__ h2, const float* __restrict__ ssrc,
                                                   const float* __restrict__ sdstv,
                                                   const int* __restrict__ bend, const int* __restrict__ sidx,
                                                   float* __restrict__ out, int n, int NS){
    const int w = threadIdx.x >> 6, lane = threadIdx.x & 63;
    const int node = blockIdx.x*4 + w;
    if (node >= n) return;
    const int r0 = node ? bend[(size_t)node*NS - 1] : 0;
    const int r1 = bend[(size_t)(node+1)*NS - 1];
    const float ss = ssrc[node];
    const bool act = lane < 20;
    float acc = 0.f, wsum = 0.f;
    int e = r0;
    for (; e + 3 < r1; e += 4){
        int j0 = sidx[e], j1 = sidx[e+1], j2 = sidx[e+2], j3 = sidx[e+3];
        float v0 = act ? h2[(size_t)j0*20 + lane] : 0.f;
        float v1 = act ? h2[(size_t)j1*20 + lane] : 0.f;
        float v2 = act ? h2[(size_t)j2*20 + lane] : 0.f;
        float v3 = act ? h2[(size_t)j3*20 + lane] : 0.f;
        float s0 = sdstv[j0], s1 = sdstv[j1], s2 = sdstv[j2], s3 = sdstv[j3];
        float w0 = __expf(lrelu(ss + s0));
        float w1 = __expf(lrelu(ss + s1));
        float w2 = __expf(lrelu(ss + s2));
        float w3 = __expf(lrelu(ss + s3));
        acc += w0*v0 + w1*v1 + w2*v2 + w3*v3;
        wsum += (w0 + w1) + (w2 + w3);
    }
    for (; e < r1; ++e){
        int j = sidx[e];
        float v = act ? h2[(size_t)j*20 + lane] : 0.f;
        float wg = __expf(lrelu(ss + sdstv[j]));
        acc += wg*v; wsum += wg;
    }
    if (act) out[(size_t)node*20 + lane] = elu_f(acc / wsum);
}

extern "C" void kernel_launch(void* const* d_in, const int* in_sizes, int n_in,
                              void* d_out, int out_size, void* d_ws, size_t ws_size,
                              hipStream_t stream){
    const float* x  = (const float*)d_in[0];
    const float* W1 = (const float*)d_in[1];
    const float* a1 = (const float*)d_in[2];
    const float* W2 = (const float*)d_in[3];
    const float* a2 = (const float*)d_in[4];
    const int*   ei = (const int*)d_in[5];
    const int n = in_sizes[0] / 512;
    const int E = in_sizes[5] / 2;
    const int* e0 = ei;
    const int* e1 = ei + E;
    const int NS = (n + (1 << SSHIFT) - 1) >> SSHIFT;   // source slices
    const int T  = n * NS;                              // bucket cells

    char* p = (char*)d_ws;
    auto alloc = [&](size_t bytes)->char*{ char* r = p; p += (bytes + 255) & ~(size_t)255; return r; };
    unsigned short* xhi  = (unsigned short*)alloc((size_t)n*512*2);   // 51.2 MB (-> hcat after gemm1)
    unsigned short* xlo  = (unsigned short*)alloc((size_t)n*512*2);   // 51.2 MB (-> h2 + CSR after gemm1)
    __half*         h_g  = (__half*)        alloc((size_t)n*512*2);   // 51.2 MB
    unsigned short* wThi = (unsigned short*)alloc((size_t)8*64*512*2);
    unsigned short* wTlo = (unsigned short*)alloc((size_t)8*64*512*2);
    float* ssrc1   = (float*)alloc((size_t)n*8*4);
    float* sdst1   = (float*)alloc((size_t)n*8*4);
    // aliases inside xlo (dead after gemm1):
    __half* hcat  = (__half*)xhi;                        // agg1 output
    float*  h2    = (float*)xlo;                         // gemm2 output: n*20*4 = 4.0 MB
    float*  ssrc2 = h2 + (size_t)n*20;
    float*  sdst2 = ssrc2 + n;
    int*    cursor = (int*)((char*)xlo + ((size_t)6 << 20));          // T*4 = 5.0 MB (cnt -> prefix -> bucket-ends)
    int*    sidx   = cursor + T;                                      // E*4 = 6.6 MB
    int*    bsum   = sidx + E;                                        // hierarchical-scan partials
    int*    bexcl  = bsum + 2048;

    // ---- phase 1: dense layer-1 GEMM (uses xhi/xlo before they are reused) ----
    const int total4 = n*512/4;
    split_x_kernel<<<(total4 + 255)/256, 256, 0, stream>>>(x, xhi, xlo, total4);
    prep_w_kernel <<<1024, 256, 0, stream>>>(W1, wThi, wTlo);
    const int mb = (n + 127)/128;
    const int nwg = mb*4;
    gemm1_mfma_kernel<<<nwg, 256, 0, stream>>>(xhi, xlo, wThi, wTlo, a1, h_g, ssrc1, sdst1, n, nwg);

    // ---- phase 2: CSR build, bucketed by (dst, src>>SSHIFT) ----
    hipMemsetAsync(cursor, 0, (size_t)T*4, stream);
    const int KCH = 192;
    hist_sliced_kernel<<<KCH*8, 256, 0, stream>>>(e0, e1, E, n, NS, cursor);
    const int NB = (T + 4095)/4096;                      // <= 512 for this size
    scan_reduce_kernel<<<NB, 256, 0, stream>>>(cursor, T, bsum);
    scan_small_kernel <<<1, 512, 0, stream>>>(bsum, NB, bexcl);
    scan_apply_kernel <<<NB, 256, 0, stream>>>(cursor, T, bexcl);
    scatter_sliced_kernel<<<KCH*8, 256, 0, stream>>>(e0, e1, E, n, NS, cursor, sidx);
    // after scatter, cursor[k] = end of bucket k

    // ---- phase 3: aggregation + layer 2 ----
    agg1_kernel<<<(n + 3)/4, 256, 0, stream>>>(h_g, ssrc1, sdst1, cursor, sidx, hcat, n, NS);
    const int nb256 = (n + 255)/256;
    gemm2_kernel<<<nb256, 256, 0, stream>>>(hcat, W2, a2, h2, ssrc2, sdst2, n);
    agg2_kernel <<<(n + 3)/4, 256, 0, stream>>>(h2, ssrc2, sdst2, cursor, sidx, (float*)d_out, n, NS);
}